// Round 7
// baseline (205.169 us; speedup 1.0000x reference)
//
#include <hip/hip_runtime.h>
#include <math.h>

typedef float f32x4 __attribute__((ext_vector_type(4)));

#define NCH 32   // scan chunks
#define CLN 32   // chunk length
#define NPOOLB 1024
#define NMEGA 512

// workspace float offsets
#define OFF_CONST 0          // 16
#define OFF_W     16         // [2][3][128] = 768
#define OFF_AL2   784        // [2][512] = 1024
#define OFF_VE    1808       // 64
#define OFF_SA    1872       // [2*16][1024] raw max = 32768
#define OFF_P     34640      // [2*16][32][512] = 524288
#define OFF_Q     558928     // 524288
#define OFF_HIN   1083216    // 524288
#define OFF_BAR   1607504    // 2 x unsigned barrier flags

#define LOG2E 1.4426950408889634f
#define LN2   0.6931471805599453f

__device__ __forceinline__ float fexp2(float x){ return __builtin_amdgcn_exp2f(x); }
__device__ __forceinline__ float flog2(float x){ return __builtin_amdgcn_logf(x); }
__device__ __forceinline__ float frcp (float x){ return __builtin_amdgcn_rcpf(x); }
__device__ __forceinline__ float fsigmoid(float x){ return frcp(1.f + fexp2(-x*LOG2E)); }
__device__ __forceinline__ float fsilu(float x){ return x * fsigmoid(x); }
__device__ __forceinline__ float fsoftplus(float x){
  return fmaxf(x, 0.f) + LN2 * flog2(1.f + fexp2(-fabsf(x)*LOG2E));
}

__device__ __forceinline__ float wave_rsum(float v){
  #pragma unroll
  for (int o = 1; o < 64; o <<= 1) v += __shfl_xor(v, o, 64);
  return v;
}
__device__ __forceinline__ float wave_rmax(float v){
  #pragma unroll
  for (int o = 1; o < 64; o <<= 1) v = fmaxf(v, __shfl_xor(v, o, 64));
  return v;
}

// ---- software grid barrier (all NMEGA blocks guaranteed resident) ----
__device__ __forceinline__ void gridbar(unsigned* cnt, unsigned* gen, unsigned nb){
  __syncthreads();
  if (threadIdx.x == 0){
    __threadfence();
    unsigned g = __hip_atomic_load(gen, __ATOMIC_ACQUIRE, __HIP_MEMORY_SCOPE_AGENT);
    unsigned a = __hip_atomic_fetch_add(cnt, 1u, __ATOMIC_ACQ_REL, __HIP_MEMORY_SCOPE_AGENT);
    if (a == nb - 1u){
      __hip_atomic_store(cnt, 0u, __ATOMIC_RELAXED, __HIP_MEMORY_SCOPE_AGENT);
      __hip_atomic_store(gen, g + 1u, __ATOMIC_RELEASE, __HIP_MEMORY_SCOPE_AGENT);
    } else {
      unsigned cur;
      do {
        __builtin_amdgcn_s_sleep(2);
        cur = __hip_atomic_load(gen, __ATOMIC_ACQUIRE, __HIP_MEMORY_SCOPE_AGENT);
      } while (cur == g);
    }
    __threadfence();
  }
  __syncthreads();
}

// ---------------- pool (persistent, nt loads, 3-row-deep prefetch) + consts ----------------
__global__ void __launch_bounds__(256) k_pool(
    const float* __restrict__ img1, const float* __restrict__ img2,
    const float* pre_w, const float* pre_b, const float* ln_g, const float* ln_b,
    const float* in_w, const float* in_b_w, const float* A_log, const float* A_b_log,
    const float* norm_w, const float* out_w, const float* post_w,
    float* __restrict__ ws){
  int t = threadIdx.x;
  if (blockIdx.x == NPOOLB){
    // ---- consts ----
    __shared__ float gw[64], gb[64], lnbs[64];
    if (t == 0){   // zero grid-barrier flags for k_mega
      ((unsigned*)(ws + OFF_BAR))[0] = 0u;
      ((unsigned*)(ws + OFF_BAR))[1] = 0u;
    }
    if (t < 64){
      float w = pre_w[t], b = pre_b[t];
      float mw = wave_rsum(w) * (1.f/64.f);
      float mb = wave_rsum(b) * (1.f/64.f);
      float wc = w - mw, bc = b - mb;
      float Av = wave_rsum(wc*wc) * (1.f/64.f);
      float Bq = wave_rsum(wc*bc) * (1.f/64.f);
      float Cq = wave_rsum(bc*bc) * (1.f/64.f);
      gw[t] = wc * ln_g[t];
      gb[t] = bc * ln_g[t];
      lnbs[t] = ln_b[t];
      if (t == 0){ ws[OFF_CONST+0] = Av; ws[OFF_CONST+1] = Bq; ws[OFF_CONST+2] = Cq; }
    }
    __syncthreads();
    {
      int br = t >> 7, e = t & 127;
      const float* iw = br ? in_b_w : in_w;
      float s1 = 0.f, s2 = 0.f, s3 = 0.f;
      for (int d = 0; d < 64; ++d){
        float w = iw[e*64 + d];
        s1 += w * gw[d]; s2 += w * gb[d]; s3 += w * lnbs[d];
      }
      ws[OFF_W + br*384 +   0 + e] = s1;
      ws[OFF_W + br*384 + 128 + e] = s2;
      ws[OFF_W + br*384 + 256 + e] = s3;
    }
    for (int i = t; i < 1024; i += 256){
      int br = i >> 9, idx = i & 511;
      const float* al = br ? A_b_log : A_log;
      ws[OFF_AL2 + i] = -expf(al[idx]) * LOG2E;
    }
    if (t < 64){
      float s = 0.f;
      for (int e = 0; e < 64; ++e) s += post_w[e] * out_w[e*64 + t];
      ws[OFF_VE + t] = s * norm_w[t];
    }
    return;
  }
  // ---- pool: 8 rows per wave, 3-row lookahead (12 nt loads in flight) ----
  int wv = t >> 6, lane = t & 63;
  int wid = blockIdx.x * 4 + wv;          // 0..4095
  int r0 = wid * 8;                       // 8 consecutive rows, same img, same b
  int img = r0 >> 14;
  int rem0 = r0 & 16383;                  // b*1024 + l0
  const float* base = (img ? img2 : img1) + (size_t)rem0 * 1024;
  const f32x4* p = (const f32x4*)base + lane;   // row stride = 256 f32x4
  f32x4 v0[4], v1[4], v2[4];
  #pragma unroll
  for (int i = 0; i < 4; ++i) v0[i] = __builtin_nontemporal_load(p +   0 + i*64);
  #pragma unroll
  for (int i = 0; i < 4; ++i) v1[i] = __builtin_nontemporal_load(p + 256 + i*64);
  #pragma unroll
  for (int i = 0; i < 4; ++i) v2[i] = __builtin_nontemporal_load(p + 512 + i*64);
  float mkeep = 0.f;
  #pragma unroll
  for (int r = 0; r < 8; ++r){
    float m = -INFINITY;
    #pragma unroll
    for (int i = 0; i < 4; ++i){
      f32x4 q = v0[i];
      m = fmaxf(m, fmaxf(fmaxf(q.x, q.y), fmaxf(q.z, q.w)));
    }
    m = wave_rmax(m);
    if (lane == r) mkeep = m;
    #pragma unroll
    for (int i = 0; i < 4; ++i){ v0[i] = v1[i]; v1[i] = v2[i]; }
    if (r < 5){
      const f32x4* q = p + (r+3)*256;
      #pragma unroll
      for (int i = 0; i < 4; ++i) v2[i] = __builtin_nontemporal_load(q + i*64);
    }
  }
  if (lane < 8){
    int b2 = rem0 >> 10, l = (rem0 & 1023) + lane;
    int pos = img ? ((16 + b2)*1024 + (1023 - l)) : (rem0 + lane);  // branch1 pre-reversed
    ws[OFF_SA + pos] = mkeep;
  }
}

// ---------------- shared proj scratch ----------------
struct Smem {
  float a1[36], a2[36], a3[36];
  float xpt[20*65];     // padded stride 65 (bank-conflict-free)
  float dtlr[32*4];
  float sxt[64*37];     // [d][ll] stride 37
  float dtt[32*64];     // [ll][d]
  float bct[32*16];     // [ll][k]
};

// recompute conv+silu+xproj+dt for one chunk into LDS (from pooled scalars only)
__device__ __forceinline__ void proj_chunk(
    int bq, int c, int br,
    const float* __restrict__ cw, const float* __restrict__ cb,
    const float* __restrict__ xpw, const float* __restrict__ dw,
    const float* __restrict__ dbv,
    const float* __restrict__ ws, Smem& S, int t){
  __syncthreads();                 // protect S from prior readers
  if (t < 36){
    int gl = c*CLN - 3 + t;
    bool ok = (gl >= 0) && (t < 35);
    float m = ok ? ws[OFF_SA + bq*1024 + gl] : 0.f;
    float Av = ws[OFF_CONST], Bq = ws[OFF_CONST+1], Cq = ws[OFF_CONST+2];
    float inv = rsqrtf(m*m*Av + 2.f*m*Bq + Cq + 1e-5f);
    S.a1[t] = ok ? m*inv : 0.f;
    S.a2[t] = ok ? inv   : 0.f;
    S.a3[t] = ok ? 1.f   : 0.f;
  }
  for (int i = t; i < 20*64; i += 512){
    int k = i >> 6, d = i & 63;
    S.xpt[k*65 + d] = xpw[i];
  }
  __syncthreads();
  {
    int d = t & 63, lq = t >> 6;
    float cw0=cw[d*4], cw1=cw[d*4+1], cw2=cw[d*4+2], cw3=cw[d*4+3];
    float cbd = cb[d];
    float W1d = ws[OFF_W + br*384 + d];
    float W2d = ws[OFF_W + br*384 + 128 + d];
    float W3d = ws[OFF_W + br*384 + 256 + d];
    #pragma unroll
    for (int j = 0; j < 4; ++j){
      int ll = lq*4 + j;
      float A1 = cw0*S.a1[ll] + cw1*S.a1[ll+1] + cw2*S.a1[ll+2] + cw3*S.a1[ll+3];
      float A2 = cw0*S.a2[ll] + cw1*S.a2[ll+1] + cw2*S.a2[ll+2] + cw3*S.a2[ll+3];
      float A3 = cw0*S.a3[ll] + cw1*S.a3[ll+1] + cw2*S.a3[ll+2] + cw3*S.a3[ll+3];
      float xc = W1d*A1 + W2d*A2 + W3d*A3 + cbd;
      S.sxt[d*37 + ll] = fsilu(xc);
    }
  }
  __syncthreads();
  {
    int ll = t >> 4, k = t & 15;
    float acc = 0.f;
    #pragma unroll 8
    for (int d = 0; d < 64; ++d) acc += S.xpt[(4+k)*65 + d] * S.sxt[d*37 + ll];
    S.bct[ll*16 + k] = acc;
  }
  if (t < 128){
    int ll = t >> 2, r = t & 3;
    float acc = 0.f;
    #pragma unroll 8
    for (int d = 0; d < 64; ++d) acc += S.xpt[r*65 + d] * S.sxt[d*37 + ll];
    S.dtlr[ll*4 + r] = acc;
  }
  __syncthreads();
  {
    int d = t & 63, lq = t >> 6;
    float w0=dw[d*4], w1=dw[d*4+1], w2=dw[d*4+2], w3=dw[d*4+3];
    float bd = dbv[d];
    #pragma unroll
    for (int j = 0; j < 4; ++j){
      int ll = lq*4 + j;
      float raw = bd + w0*S.dtlr[ll*4] + w1*S.dtlr[ll*4+1]
                     + w2*S.dtlr[ll*4+2] + w3*S.dtlr[ll*4+3];
      S.dtt[ll*64 + d] = fsoftplus(raw);
    }
  }
  __syncthreads();
}

// ---------------- K2: everything after the pool, one kernel, 2 grid barriers ----------------
__global__ void __launch_bounds__(512) k_mega(
    const float* conv_w, const float* conv_b, const float* convb_w, const float* convb_b,
    const float* xproj_w, const float* xprojb_w,
    const float* dt_w, const float* dt_b, const float* dtb_w, const float* dtb_b,
    const float* Dp, const float* Dp_b, const float* post_b,
    float* __restrict__ ws, float* __restrict__ out){
  __shared__ Smem S;
  __shared__ float ylds[CLN*65];
  unsigned* bar = (unsigned*)(ws + OFF_BAR);
  int bi = blockIdx.x;                 // b*32 + c (output tile)
  int c = bi & 31, b = bi >> 5;
  int t = threadIdx.x;
  int lane = t & 63, wv = t >> 6;
  int d = wv*8 + (lane >> 3), n = lane & 7;
  int taskF = b*32 + c;
  int taskB = (b+16)*32 + (31-c);
  // ---- phase 1a: fwd chunk -> P,Q ----
  proj_chunk(b, c, 0, conv_w, conv_b, xproj_w, dt_w, dt_b, ws, S, t);
  {
    float A2r = ws[OFF_AL2 + t];
    float P = 1.f, Q = 0.f;
    #pragma unroll 4
    for (int tt = 0; tt < CLN; ++tt){
      float dtv = S.dtt[tt*64 + d];
      float xv  = S.sxt[d*37 + tt];
      float bv  = S.bct[tt*16 + n];
      float da  = fexp2(dtv * A2r);
      Q = fmaf(da, Q, dtv * bv * xv);
      P *= da;
    }
    ws[OFF_P + (size_t)taskF*512 + t] = P;
    ws[OFF_Q + (size_t)taskF*512 + t] = Q;
  }
  // ---- phase 1b: bwd chunk -> P,Q (LDS state kept for phase 3a) ----
  proj_chunk(b+16, 31-c, 1, convb_w, convb_b, xprojb_w, dtb_w, dtb_b, ws, S, t);
  {
    float A2r = ws[OFF_AL2 + 512 + t];
    float P = 1.f, Q = 0.f;
    #pragma unroll 4
    for (int tt = 0; tt < CLN; ++tt){
      float dtv = S.dtt[tt*64 + d];
      float xv  = S.sxt[d*37 + tt];
      float bv  = S.bct[tt*16 + n];
      float da  = fexp2(dtv * A2r);
      Q = fmaf(da, Q, dtv * bv * xv);
      P *= da;
    }
    ws[OFF_P + (size_t)taskB*512 + t] = P;
    ws[OFF_Q + (size_t)taskB*512 + t] = Q;
  }
  gridbar(bar, bar + 1, NMEGA);
  // ---- phase 2: chunk-prefix combine (32 blocks, one bq each) ----
  if (bi < 32){
    int bq = bi;
    size_t base = (size_t)bq*NCH*512 + t;
    float P[NCH], Q[NCH];
    #pragma unroll
    for (int cc = 0; cc < NCH; ++cc){
      P[cc] = ws[OFF_P + base + (size_t)cc*512];
      Q[cc] = ws[OFF_Q + base + (size_t)cc*512];
    }
    float h = 0.f;
    #pragma unroll
    for (int cc = 0; cc < NCH; ++cc){
      ws[OFF_HIN + base + (size_t)cc*512] = h;
      h = fmaf(P[cc], h, Q[cc]);
    }
  }
  gridbar(bar, bar + 1, NMEGA);
  // ---- phase 3a: bwd replay from RESIDENT LDS state ----
  {
    float A2r = ws[OFF_AL2 + 512 + t];
    float h   = ws[OFF_HIN + (size_t)taskB*512 + t];
    float Dpd = Dp_b[d];
    float W1z = ws[OFF_W + 384 +   0 + 64 + d];
    float W2z = ws[OFF_W + 384 + 128 + 64 + d];
    float W3z = ws[OFF_W + 384 + 256 + 64 + d];
    #pragma unroll 4
    for (int tt = 0; tt < CLN; ++tt){
      float dtv = S.dtt[tt*64 + d];
      float xv  = S.sxt[d*37 + tt];
      float bv  = S.bct[tt*16 + n];
      float cv  = S.bct[tt*16 + 8 + n];
      float da  = fexp2(dtv * A2r);
      h = fmaf(da, h, dtv * bv * xv);
      float pv = h * cv;
      pv += __shfl_xor(pv, 1, 64);
      pv += __shfl_xor(pv, 2, 64);
      pv += __shfl_xor(pv, 4, 64);
      if (n == 0){
        float y = pv + Dpd * xv;
        float zv = S.a1[tt+3]*W1z + S.a2[tt+3]*W2z + W3z;
        ylds[(31-tt)*65 + d] = y * fsilu(zv);
      }
    }
  }
  // ---- phase 3b: fwd recompute + replay, accumulate ----
  proj_chunk(b, c, 0, conv_w, conv_b, xproj_w, dt_w, dt_b, ws, S, t);
  {
    float A2r = ws[OFF_AL2 + t];
    float h   = ws[OFF_HIN + (size_t)taskF*512 + t];
    float Dpd = Dp[d];
    float W1z = ws[OFF_W +   0 + 64 + d];
    float W2z = ws[OFF_W + 128 + 64 + d];
    float W3z = ws[OFF_W + 256 + 64 + d];
    #pragma unroll 4
    for (int tt = 0; tt < CLN; ++tt){
      float dtv = S.dtt[tt*64 + d];
      float xv  = S.sxt[d*37 + tt];
      float bv  = S.bct[tt*16 + n];
      float cv  = S.bct[tt*16 + 8 + n];
      float da  = fexp2(dtv * A2r);
      h = fmaf(da, h, dtv * bv * xv);
      float pv = h * cv;
      pv += __shfl_xor(pv, 1, 64);
      pv += __shfl_xor(pv, 2, 64);
      pv += __shfl_xor(pv, 4, 64);
      if (n == 0){
        float y = pv + Dpd * xv;
        float zv = S.a1[tt+3]*W1z + S.a2[tt+3]*W2z + W3z;
        ylds[tt*65 + d] += y * fsilu(zv);
      }
    }
  }
  __syncthreads();
  // ---- epilogue: rmsnorm + collapsed matvec + sigmoid; 8 waves x 4 rows ----
  float ve = ws[OFF_VE + lane];
  float pb = post_b[0];
  #pragma unroll
  for (int j = 0; j < 4; ++j){
    int row = wv*4 + j;
    float v = ylds[row*65 + lane];
    float ss = v*v, dp = v*ve;
    #pragma unroll
    for (int o = 1; o < 64; o <<= 1){
      ss += __shfl_xor(ss, o, 64);
      dp += __shfl_xor(dp, o, 64);
    }
    if (lane == 0){
      float rstd = rsqrtf(ss*(1.f/64.f) + 1e-5f);
      out[b*1024 + c*CLN + row] = fsigmoid(dp*rstd + pb);
    }
  }
}

extern "C" void kernel_launch(void* const* d_in, const int* in_sizes, int n_in,
                              void* d_out, int out_size, void* d_ws, size_t ws_size,
                              hipStream_t stream){
  const float* img1      = (const float*)d_in[0];
  const float* img2      = (const float*)d_in[1];
  const float* pre_w     = (const float*)d_in[2];
  const float* pre_b     = (const float*)d_in[3];
  const float* ln_g      = (const float*)d_in[4];
  const float* ln_b      = (const float*)d_in[5];
  const float* in_w      = (const float*)d_in[6];
  const float* in_b_w    = (const float*)d_in[7];
  const float* conv_w    = (const float*)d_in[8];
  const float* conv_bias = (const float*)d_in[9];
  const float* convb_w   = (const float*)d_in[10];
  const float* convb_bias= (const float*)d_in[11];
  const float* xproj_w   = (const float*)d_in[12];
  const float* xprojb_w  = (const float*)d_in[13];
  const float* dt_w      = (const float*)d_in[14];
  const float* dt_bias   = (const float*)d_in[15];
  const float* dtb_w     = (const float*)d_in[16];
  const float* dtb_bias  = (const float*)d_in[17];
  const float* A_log     = (const float*)d_in[18];
  const float* A_b_log   = (const float*)d_in[19];
  const float* Dp        = (const float*)d_in[20];
  const float* Dp_b      = (const float*)d_in[21];
  const float* norm_w    = (const float*)d_in[22];
  const float* out_w     = (const float*)d_in[23];
  const float* post_w    = (const float*)d_in[24];
  const float* post_b    = (const float*)d_in[25];
  float* ws  = (float*)d_ws;
  float* out = (float*)d_out;

  k_pool<<<NPOOLB+1, 256, 0, stream>>>(img1, img2, pre_w, pre_b, ln_g, ln_b,
                                       in_w, in_b_w, A_log, A_b_log,
                                       norm_w, out_w, post_w, ws);
  k_mega<<<NMEGA, 512, 0, stream>>>(conv_w, conv_bias, convb_w, convb_bias,
                                    xproj_w, xprojb_w, dt_w, dt_bias, dtb_w, dtb_bias,
                                    Dp, Dp_b, post_b, ws, out);
}

// Round 8
// 83.230 us; speedup vs baseline: 2.4651x; 2.4651x over previous
//
#include <hip/hip_runtime.h>
#include <math.h>

typedef float f32x4 __attribute__((ext_vector_type(4)));

#define NCH 32   // scan chunks
#define CLN 32   // chunk length

// workspace float offsets (~4.3 MB)
#define OFF_SA 0          // [32][1024] raw row max = 32768
#define OFF_P  32768      // [32*32][512] = 524288
#define OFF_Q  557056     // 524288

#define LOG2E 1.4426950408889634f
#define LN2   0.6931471805599453f

__device__ __forceinline__ float fexp2(float x){ return __builtin_amdgcn_exp2f(x); }
__device__ __forceinline__ float flog2(float x){ return __builtin_amdgcn_logf(x); }
__device__ __forceinline__ float frcp (float x){ return __builtin_amdgcn_rcpf(x); }
__device__ __forceinline__ float fsigmoid(float x){ return frcp(1.f + fexp2(-x*LOG2E)); }
__device__ __forceinline__ float fsilu(float x){ return x * fsigmoid(x); }
__device__ __forceinline__ float fsoftplus(float x){
  return fmaxf(x, 0.f) + LN2 * flog2(1.f + fexp2(-fabsf(x)*LOG2E));
}

__device__ __forceinline__ float wave_rsum(float v){
  #pragma unroll
  for (int o = 1; o < 64; o <<= 1) v += __shfl_xor(v, o, 64);
  return v;
}
__device__ __forceinline__ float wave_rmax(float v){
  #pragma unroll
  for (int o = 1; o < 64; o <<= 1) v = fmaxf(v, __shfl_xor(v, o, 64));
  return v;
}

// ---------------- shared scratch (per block) ----------------
struct Smem {
  float a1[36], a2[36], a3[36];
  float xpt[20*65];     // padded stride 65
  float dtlr[32*4];
  float sxt[64*37];     // [d][ll] stride 37
  float dtt[32*64];     // [ll][d]
  float bct[32*16];     // [ll][k]
  // per-block consts
  float gw[64], gb[64], lnbs[64];
  float W[2][384];      // [branch][{W1,W2,W3}x128]
  float cst[4];         // Av, Bq, Cq
};

// layernorm-collapse base consts (wave 0)
__device__ __forceinline__ void consts_ln(Smem& S, int t,
    const float* pre_w, const float* pre_b, const float* ln_g, const float* ln_b){
  if (t < 64){
    float w = pre_w[t], b = pre_b[t];
    float mw = wave_rsum(w) * (1.f/64.f);
    float mb = wave_rsum(b) * (1.f/64.f);
    float wc = w - mw, bc = b - mb;
    float Av = wave_rsum(wc*wc) * (1.f/64.f);
    float Bq = wave_rsum(wc*bc) * (1.f/64.f);
    float Cq = wave_rsum(bc*bc) * (1.f/64.f);
    S.gw[t] = wc * ln_g[t];
    S.gb[t] = bc * ln_g[t];
    S.lnbs[t] = ln_b[t];
    if (t == 0){ S.cst[0] = Av; S.cst[1] = Bq; S.cst[2] = Cq; }
  }
}
// W vectors for one branch (threads 0..127); needs consts_ln + syncthreads first
__device__ __forceinline__ void consts_W(Smem& S, int t, const float* iw, int slot){
  if (t < 128){
    float s1 = 0.f, s2 = 0.f, s3 = 0.f;
    #pragma unroll 8
    for (int d = 0; d < 64; ++d){
      float w = iw[t*64 + d];
      s1 += w * S.gw[d]; s2 += w * S.gb[d]; s3 += w * S.lnbs[d];
    }
    S.W[slot][      t] = s1;
    S.W[slot][128 + t] = s2;
    S.W[slot][256 + t] = s3;
  }
}

// conv+silu+xproj+dt for one chunk; assumes S.a1/a2/a3 and S.W[slot] ready.
// Caller must __syncthreads() before (protects S reuse).
__device__ __forceinline__ void proj_body(
    Smem& S, int t, int slot,
    const float* __restrict__ cw, const float* __restrict__ cb,
    const float* __restrict__ xpw, const float* __restrict__ dw,
    const float* __restrict__ dbv){
  for (int i = t; i < 20*64; i += 512){
    int k = i >> 6, d = i & 63;
    S.xpt[k*65 + d] = xpw[i];
  }
  __syncthreads();
  {
    int d = t & 63, lq = t >> 6;
    float cw0=cw[d*4], cw1=cw[d*4+1], cw2=cw[d*4+2], cw3=cw[d*4+3];
    float cbd = cb[d];
    float W1d = S.W[slot][d], W2d = S.W[slot][128+d], W3d = S.W[slot][256+d];
    #pragma unroll
    for (int j = 0; j < 4; ++j){
      int ll = lq*4 + j;
      float A1 = cw0*S.a1[ll] + cw1*S.a1[ll+1] + cw2*S.a1[ll+2] + cw3*S.a1[ll+3];
      float A2 = cw0*S.a2[ll] + cw1*S.a2[ll+1] + cw2*S.a2[ll+2] + cw3*S.a2[ll+3];
      float A3 = cw0*S.a3[ll] + cw1*S.a3[ll+1] + cw2*S.a3[ll+2] + cw3*S.a3[ll+3];
      float xc = W1d*A1 + W2d*A2 + W3d*A3 + cbd;
      S.sxt[d*37 + ll] = fsilu(xc);
    }
  }
  __syncthreads();
  {
    int ll = t >> 4, k = t & 15;
    float acc = 0.f;
    #pragma unroll 8
    for (int d = 0; d < 64; ++d) acc += S.xpt[(4+k)*65 + d] * S.sxt[d*37 + ll];
    S.bct[ll*16 + k] = acc;
  }
  if (t < 128){
    int ll = t >> 2, r = t & 3;
    float acc = 0.f;
    #pragma unroll 8
    for (int d = 0; d < 64; ++d) acc += S.xpt[r*65 + d] * S.sxt[d*37 + ll];
    S.dtlr[ll*4 + r] = acc;
  }
  __syncthreads();
  {
    int d = t & 63, lq = t >> 6;
    float w0=dw[d*4], w1=dw[d*4+1], w2=dw[d*4+2], w3=dw[d*4+3];
    float bd = dbv[d];
    #pragma unroll
    for (int j = 0; j < 4; ++j){
      int ll = lq*4 + j;
      float raw = bd + w0*S.dtlr[ll*4] + w1*S.dtlr[ll*4+1]
                     + w2*S.dtlr[ll*4+2] + w3*S.dtlr[ll*4+3];
      S.dtt[ll*64 + d] = fsoftplus(raw);
    }
  }
  __syncthreads();
}

// ---------------- K1: fused pool + consts + proj + P,Q ----------------
__global__ void __launch_bounds__(512) k_projA(
    const float* __restrict__ img1, const float* __restrict__ img2,
    const float* pre_w, const float* pre_b, const float* ln_g, const float* ln_b,
    const float* in_w, const float* in_b_w, const float* A_log, const float* A_b_log,
    const float* conv_w, const float* conv_b, const float* convb_w, const float* convb_b,
    const float* xproj_w, const float* xprojb_w,
    const float* dt_w, const float* dt_b, const float* dtb_w, const float* dtb_b,
    float* __restrict__ ws){
  __shared__ Smem S;
  int bi = blockIdx.x;                 // bq*32 + c
  int c = bi & 31, bq = bi >> 5, br = bq >> 4, b = bq & 15;
  int t = threadIdx.x;
  int wv = t >> 6, lane = t & 63;
  // ---- pool: each wave loads its rows (35 rows, incl 3-row halo) ----
  const float* img = br ? img2 : img1;
  #pragma unroll
  for (int k = 0; k < 5; ++k){
    int i = wv + k*8;
    if (i < 35){
      bool valid = (c > 0) || (i >= 3);
      if (valid){
        int l = br ? (1026 - c*32 - i) : (c*32 - 3 + i);
        const f32x4* rp = (const f32x4*)(img + ((size_t)(b*1024 + l))*1024) + lane;
        f32x4 q0 = __builtin_nontemporal_load(rp +   0);
        f32x4 q1 = __builtin_nontemporal_load(rp +  64);
        f32x4 q2 = __builtin_nontemporal_load(rp + 128);
        f32x4 q3 = __builtin_nontemporal_load(rp + 192);
        float m = fmaxf(fmaxf(fmaxf(q0.x,q0.y), fmaxf(q0.z,q0.w)),
                        fmaxf(fmaxf(q1.x,q1.y), fmaxf(q1.z,q1.w)));
        m = fmaxf(m, fmaxf(fmaxf(fmaxf(q2.x,q2.y), fmaxf(q2.z,q2.w)),
                           fmaxf(fmaxf(q3.x,q3.y), fmaxf(q3.z,q3.w))));
        m = wave_rmax(m);
        if (lane == 0){
          S.a1[i] = m;
          if (i >= 3) ws[OFF_SA + bq*1024 + (c*32 - 3 + i)] = m;
        }
      } else if (lane == 0) S.a1[i] = 0.f;
    }
  }
  // ---- consts (overlap with load drain) ----
  consts_ln(S, t, pre_w, pre_b, ln_g, ln_b);
  __syncthreads();
  consts_W(S, t, br ? in_b_w : in_w, 0);
  float A2r = -fexp2((br ? A_b_log : A_log)[t] * LOG2E) * LOG2E;
  __syncthreads();
  // ---- convert raw max -> a1/a2/a3 ----
  if (t < 36){
    bool ok = (t < 35) && ((c > 0) || (t >= 3));
    float m = ok ? S.a1[t] : 0.f;
    float Av = S.cst[0], Bq = S.cst[1], Cq = S.cst[2];
    float inv = rsqrtf(m*m*Av + 2.f*m*Bq + Cq + 1e-5f);
    S.a1[t] = ok ? m*inv : 0.f;
    S.a2[t] = ok ? inv   : 0.f;
    S.a3[t] = ok ? 1.f   : 0.f;
  }
  proj_body(S, t, 0,
            br ? convb_w : conv_w,  br ? convb_b : conv_b,
            br ? xprojb_w : xproj_w, br ? dtb_w : dt_w, br ? dtb_b : dt_b);
  // ---- per-chunk (P,Q) ----
  int d = wv*8 + (lane >> 3), n = lane & 7;
  float P = 1.f, Q = 0.f;
  #pragma unroll 4
  for (int tt = 0; tt < CLN; ++tt){
    float dtv = S.dtt[tt*64 + d];
    float xv  = S.sxt[d*37 + tt];
    float bv  = S.bct[tt*16 + n];
    float da  = fexp2(dtv * A2r);
    Q = fmaf(da, Q, dtv * bv * xv);
    P *= da;
  }
  ws[OFF_P + (size_t)bi*512 + t] = P;
  ws[OFF_Q + (size_t)bi*512 + t] = Q;
}

// ---------------- K2: consts + inline prefix + 2x(proj+replay) + epilogue ----------------
__global__ void __launch_bounds__(512) k_projC(
    const float* pre_w, const float* pre_b, const float* ln_g, const float* ln_b,
    const float* in_w, const float* in_b_w, const float* A_log, const float* A_b_log,
    const float* conv_w, const float* conv_b, const float* convb_w, const float* convb_b,
    const float* xproj_w, const float* xprojb_w,
    const float* dt_w, const float* dt_b, const float* dtb_w, const float* dtb_b,
    const float* Dp, const float* Dp_b,
    const float* norm_w, const float* out_w, const float* post_w, const float* post_b,
    float* __restrict__ ws, float* __restrict__ out){
  __shared__ Smem S;
  __shared__ float ylds[CLN*65];
  __shared__ float vew[64];
  int bi = blockIdx.x;                 // b*32 + c (output tile)
  int c = bi & 31, b = bi >> 5;
  int t = threadIdx.x;
  int lane = t & 63, wv = t >> 6;
  int d = wv*8 + (lane >> 3), n = lane & 7;
  // ---- per-block consts ----
  consts_ln(S, t, pre_w, pre_b, ln_g, ln_b);
  __syncthreads();
  consts_W(S, t, in_w, 0);
  consts_W(S, t, in_b_w, 1);
  if (t < 64){
    float s = 0.f;
    #pragma unroll 8
    for (int e = 0; e < 64; ++e) s += post_w[e] * out_w[e*64 + t];
    vew[t] = s * norm_w[t];
  }
  float A2r0 = -fexp2(A_log[t]   * LOG2E) * LOG2E;
  float A2r1 = -fexp2(A_b_log[t] * LOG2E) * LOG2E;
  #pragma unroll
  for (int pass = 0; pass < 2; ++pass){
    int bq = pass ? b + 16 : b;
    int ch = pass ? 31 - c : c;
    __syncthreads();                 // protect S from prior readers
    if (t < 36){
      int gl = ch*CLN - 3 + t;
      bool ok = (gl >= 0) && (t < 35);
      float m = ok ? ws[OFF_SA + bq*1024 + gl] : 0.f;
      float Av = S.cst[0], Bq = S.cst[1], Cq = S.cst[2];
      float inv = rsqrtf(m*m*Av + 2.f*m*Bq + Cq + 1e-5f);
      S.a1[t] = ok ? m*inv : 0.f;
      S.a2[t] = ok ? inv   : 0.f;
      S.a3[t] = ok ? 1.f   : 0.f;
    }
    proj_body(S, t, pass,
              pass ? convb_w : conv_w,  pass ? convb_b : conv_b,
              pass ? xprojb_w : xproj_w, pass ? dtb_w : dt_w, pass ? dtb_b : dt_b);
    // ---- inline chunk-prefix: h = scan over chunks < ch (batched loads) ----
    float h = 0.f;
    {
      const float* Pp = ws + OFF_P + (size_t)bq*NCH*512 + t;
      const float* Qp = ws + OFF_Q + (size_t)bq*NCH*512 + t;
      #pragma unroll
      for (int base = 0; base < 32; base += 8){
        if (base < ch){                      // wave-uniform
          float Pa[8], Qa[8];
          #pragma unroll
          for (int j = 0; j < 8; ++j){
            Pa[j] = Pp[(base+j)*512];
            Qa[j] = Qp[(base+j)*512];
          }
          #pragma unroll
          for (int j = 0; j < 8; ++j)
            h = (base + j < ch) ? fmaf(Pa[j], h, Qa[j]) : h;
        }
      }
    }
    // ---- replay + gate ----
    float A2r = pass ? A2r1 : A2r0;
    float Dpd = (pass ? Dp_b : Dp)[d];
    float W1z = S.W[pass][      64 + d];
    float W2z = S.W[pass][128 + 64 + d];
    float W3z = S.W[pass][256 + 64 + d];
    #pragma unroll 4
    for (int tt = 0; tt < CLN; ++tt){
      float dtv = S.dtt[tt*64 + d];
      float xv  = S.sxt[d*37 + tt];
      float bv  = S.bct[tt*16 + n];
      float cv  = S.bct[tt*16 + 8 + n];
      float da  = fexp2(dtv * A2r);
      h = fmaf(da, h, dtv * bv * xv);
      float pv = h * cv;
      pv += __shfl_xor(pv, 1, 64);
      pv += __shfl_xor(pv, 2, 64);
      pv += __shfl_xor(pv, 4, 64);
      if (n == 0){
        float y = pv + Dpd * xv;
        float zv = S.a1[tt+3]*W1z + S.a2[tt+3]*W2z + W3z;
        float g = fsilu(zv);
        int row = pass ? (31 - tt) : tt;
        if (pass == 0) ylds[row*65 + d] = y * g;
        else           ylds[row*65 + d] += y * g;
      }
    }
  }
  __syncthreads();
  // ---- epilogue: rmsnorm + collapsed matvec + sigmoid ----
  float ve = vew[lane];
  float pb = post_b[0];
  #pragma unroll
  for (int j = 0; j < 4; ++j){
    int row = wv*4 + j;
    float v = ylds[row*65 + lane];
    float ss = v*v, dp = v*ve;
    #pragma unroll
    for (int o = 1; o < 64; o <<= 1){
      ss += __shfl_xor(ss, o, 64);
      dp += __shfl_xor(dp, o, 64);
    }
    if (lane == 0){
      float rstd = rsqrtf(ss*(1.f/64.f) + 1e-5f);
      out[b*1024 + c*CLN + row] = fsigmoid(dp*rstd + pb);
    }
  }
}

extern "C" void kernel_launch(void* const* d_in, const int* in_sizes, int n_in,
                              void* d_out, int out_size, void* d_ws, size_t ws_size,
                              hipStream_t stream){
  const float* img1      = (const float*)d_in[0];
  const float* img2      = (const float*)d_in[1];
  const float* pre_w     = (const float*)d_in[2];
  const float* pre_b     = (const float*)d_in[3];
  const float* ln_g      = (const float*)d_in[4];
  const float* ln_b      = (const float*)d_in[5];
  const float* in_w      = (const float*)d_in[6];
  const float* in_b_w    = (const float*)d_in[7];
  const float* conv_w    = (const float*)d_in[8];
  const float* conv_bias = (const float*)d_in[9];
  const float* convb_w   = (const float*)d_in[10];
  const float* convb_bias= (const float*)d_in[11];
  const float* xproj_w   = (const float*)d_in[12];
  const float* xprojb_w  = (const float*)d_in[13];
  const float* dt_w      = (const float*)d_in[14];
  const float* dt_bias   = (const float*)d_in[15];
  const float* dtb_w     = (const float*)d_in[16];
  const float* dtb_bias  = (const float*)d_in[17];
  const float* A_log     = (const float*)d_in[18];
  const float* A_b_log   = (const float*)d_in[19];
  const float* Dp        = (const float*)d_in[20];
  const float* Dp_b      = (const float*)d_in[21];
  const float* norm_w    = (const float*)d_in[22];
  const float* out_w     = (const float*)d_in[23];
  const float* post_w    = (const float*)d_in[24];
  const float* post_b    = (const float*)d_in[25];
  float* ws  = (float*)d_ws;
  float* out = (float*)d_out;

  k_projA<<<1024, 512, 0, stream>>>(img1, img2, pre_w, pre_b, ln_g, ln_b,
                                    in_w, in_b_w, A_log, A_b_log,
                                    conv_w, conv_bias, convb_w, convb_bias,
                                    xproj_w, xprojb_w, dt_w, dt_bias, dtb_w, dtb_bias,
                                    ws);
  k_projC<<<512, 512, 0, stream>>>(pre_w, pre_b, ln_g, ln_b,
                                   in_w, in_b_w, A_log, A_b_log,
                                   conv_w, conv_bias, convb_w, convb_bias,
                                   xproj_w, xprojb_w, dt_w, dt_bias, dtb_w, dtb_bias,
                                   Dp, Dp_b, norm_w, out_w, post_w, post_b,
                                   ws, out);
}

// Round 9
// 80.030 us; speedup vs baseline: 2.5636x; 1.0400x over previous
//
#include <hip/hip_runtime.h>
#include <math.h>

typedef float f32x4 __attribute__((ext_vector_type(4)));

#define NCH 32   // scan chunks
#define CLN 32   // chunk length

// workspace float offsets (~23.3 MB)
#define OFF_P   0          // [1024][512]
#define OFF_Q   524288     // [1024][512]
#define OFF_DTT 1048576    // [1024][2048]  dt tiles [tt][d]
#define OFF_SXT 3145728    // [1024][2048]  silu(conv(x)) tiles [d][tt]
#define OFF_BCT 5242880    // [1024][512]   B/C tiles [tt][k]
#define OFF_AN  5767168    // [1024][64]    normalized pool scalars a1[32],a2[32]

#define LOG2E 1.4426950408889634f
#define LN2   0.6931471805599453f

__device__ __forceinline__ float fexp2(float x){ return __builtin_amdgcn_exp2f(x); }
__device__ __forceinline__ float flog2(float x){ return __builtin_amdgcn_logf(x); }
__device__ __forceinline__ float frcp (float x){ return __builtin_amdgcn_rcpf(x); }
__device__ __forceinline__ float fsigmoid(float x){ return frcp(1.f + fexp2(-x*LOG2E)); }
__device__ __forceinline__ float fsilu(float x){ return x * fsigmoid(x); }
__device__ __forceinline__ float fsoftplus(float x){
  return fmaxf(x, 0.f) + LN2 * flog2(1.f + fexp2(-fabsf(x)*LOG2E));
}

__device__ __forceinline__ float wave_rsum(float v){
  #pragma unroll
  for (int o = 1; o < 64; o <<= 1) v += __shfl_xor(v, o, 64);
  return v;
}
__device__ __forceinline__ float wave_rmax(float v){
  #pragma unroll
  for (int o = 1; o < 64; o <<= 1) v = fmaxf(v, __shfl_xor(v, o, 64));
  return v;
}

// ---------------- shared scratch for projA ----------------
struct Smem {
  float a1[36], a2[36], a3[36];
  float xpt[20*65];     // padded stride 65
  float dtlr[32*4];
  float sxt[64*37];     // [d][ll] stride 37
  float dtt[32*64];     // [ll][d]
  float bct[32*16];     // [ll][k]
  float gw[64], gb[64], lnbs[64];
  float W[384];         // this branch's {W1,W2,W3}x128
  float cst[4];         // Av, Bq, Cq
};

__device__ __forceinline__ void consts_ln(float* gw, float* gb, float* lnbs, float* cst, int t,
    const float* pre_w, const float* pre_b, const float* ln_g, const float* ln_b){
  if (t < 64){
    float w = pre_w[t], b = pre_b[t];
    float mw = wave_rsum(w) * (1.f/64.f);
    float mb = wave_rsum(b) * (1.f/64.f);
    float wc = w - mw, bc = b - mb;
    float Av = wave_rsum(wc*wc) * (1.f/64.f);
    float Bq = wave_rsum(wc*bc) * (1.f/64.f);
    float Cq = wave_rsum(bc*bc) * (1.f/64.f);
    gw[t] = wc * ln_g[t];
    gb[t] = bc * ln_g[t];
    lnbs[t] = ln_b[t];
    if (t == 0){ cst[0] = Av; cst[1] = Bq; cst[2] = Cq; }
  }
}

// conv+silu+xproj+dt for one chunk; assumes S.a1/a2/a3 and S.W ready.
__device__ __forceinline__ void proj_body(
    Smem& S, int t,
    const float* __restrict__ cw, const float* __restrict__ cb,
    const float* __restrict__ xpw, const float* __restrict__ dw,
    const float* __restrict__ dbv){
  for (int i = t; i < 20*64; i += 512){
    int k = i >> 6, d = i & 63;
    S.xpt[k*65 + d] = xpw[i];
  }
  __syncthreads();
  {
    int d = t & 63, lq = t >> 6;
    float cw0=cw[d*4], cw1=cw[d*4+1], cw2=cw[d*4+2], cw3=cw[d*4+3];
    float cbd = cb[d];
    float W1d = S.W[d], W2d = S.W[128+d], W3d = S.W[256+d];
    #pragma unroll
    for (int j = 0; j < 4; ++j){
      int ll = lq*4 + j;
      float A1 = cw0*S.a1[ll] + cw1*S.a1[ll+1] + cw2*S.a1[ll+2] + cw3*S.a1[ll+3];
      float A2 = cw0*S.a2[ll] + cw1*S.a2[ll+1] + cw2*S.a2[ll+2] + cw3*S.a2[ll+3];
      float A3 = cw0*S.a3[ll] + cw1*S.a3[ll+1] + cw2*S.a3[ll+2] + cw3*S.a3[ll+3];
      float xc = W1d*A1 + W2d*A2 + W3d*A3 + cbd;
      S.sxt[d*37 + ll] = fsilu(xc);
    }
  }
  __syncthreads();
  {
    int ll = t >> 4, k = t & 15;
    float acc = 0.f;
    #pragma unroll 8
    for (int d = 0; d < 64; ++d) acc += S.xpt[(4+k)*65 + d] * S.sxt[d*37 + ll];
    S.bct[ll*16 + k] = acc;
  }
  if (t < 128){
    int ll = t >> 2, r = t & 3;
    float acc = 0.f;
    #pragma unroll 8
    for (int d = 0; d < 64; ++d) acc += S.xpt[r*65 + d] * S.sxt[d*37 + ll];
    S.dtlr[ll*4 + r] = acc;
  }
  __syncthreads();
  {
    int d = t & 63, lq = t >> 6;
    float w0=dw[d*4], w1=dw[d*4+1], w2=dw[d*4+2], w3=dw[d*4+3];
    float bd = dbv[d];
    #pragma unroll
    for (int j = 0; j < 4; ++j){
      int ll = lq*4 + j;
      float raw = bd + w0*S.dtlr[ll*4] + w1*S.dtlr[ll*4+1]
                     + w2*S.dtlr[ll*4+2] + w3*S.dtlr[ll*4+3];
      S.dtt[ll*64 + d] = fsoftplus(raw);
    }
  }
  __syncthreads();
}

// ---------------- K1: fused pool + consts + proj + persist tiles + P,Q ----------------
__global__ void __launch_bounds__(512) k_projA(
    const float* __restrict__ img1, const float* __restrict__ img2,
    const float* pre_w, const float* pre_b, const float* ln_g, const float* ln_b,
    const float* in_w, const float* in_b_w, const float* A_log, const float* A_b_log,
    const float* conv_w, const float* conv_b, const float* convb_w, const float* convb_b,
    const float* xproj_w, const float* xprojb_w,
    const float* dt_w, const float* dt_b, const float* dtb_w, const float* dtb_b,
    float* __restrict__ ws){
  __shared__ __align__(16) Smem S;
  int bi = blockIdx.x;                 // bq*32 + c
  int c = bi & 31, bq = bi >> 5, br = bq >> 4, b = bq & 15;
  int t = threadIdx.x;
  int wv = t >> 6, lane = t & 63;
  // ---- pool: each wave loads its rows (35 rows incl 3-row halo) ----
  const float* img = br ? img2 : img1;
  #pragma unroll
  for (int k = 0; k < 5; ++k){
    int i = wv + k*8;
    if (i < 35){
      bool valid = (c > 0) || (i >= 3);
      if (valid){
        int l = br ? (1026 - c*32 - i) : (c*32 - 3 + i);
        const f32x4* rp = (const f32x4*)(img + ((size_t)(b*1024 + l))*1024) + lane;
        f32x4 q0 = __builtin_nontemporal_load(rp +   0);
        f32x4 q1 = __builtin_nontemporal_load(rp +  64);
        f32x4 q2 = __builtin_nontemporal_load(rp + 128);
        f32x4 q3 = __builtin_nontemporal_load(rp + 192);
        float m = fmaxf(fmaxf(fmaxf(q0.x,q0.y), fmaxf(q0.z,q0.w)),
                        fmaxf(fmaxf(q1.x,q1.y), fmaxf(q1.z,q1.w)));
        m = fmaxf(m, fmaxf(fmaxf(fmaxf(q2.x,q2.y), fmaxf(q2.z,q2.w)),
                           fmaxf(fmaxf(q3.x,q3.y), fmaxf(q3.z,q3.w))));
        m = wave_rmax(m);
        if (lane == 0) S.a1[i] = m;
      } else if (lane == 0) S.a1[i] = 0.f;
    }
  }
  // ---- consts (overlap with load drain) ----
  consts_ln(S.gw, S.gb, S.lnbs, S.cst, t, pre_w, pre_b, ln_g, ln_b);
  __syncthreads();
  if (t < 128){
    const float* iw = br ? in_b_w : in_w;
    float s1 = 0.f, s2 = 0.f, s3 = 0.f;
    #pragma unroll 8
    for (int d = 0; d < 64; ++d){
      float w = iw[t*64 + d];
      s1 += w * S.gw[d]; s2 += w * S.gb[d]; s3 += w * S.lnbs[d];
    }
    S.W[      t] = s1;
    S.W[128 + t] = s2;
    S.W[256 + t] = s3;
  }
  float A2r = -fexp2((br ? A_b_log : A_log)[t] * LOG2E) * LOG2E;
  __syncthreads();
  // ---- convert raw max -> a1/a2/a3 ----
  if (t < 36){
    bool ok = (t < 35) && ((c > 0) || (t >= 3));
    float m = ok ? S.a1[t] : 0.f;
    float Av = S.cst[0], Bq = S.cst[1], Cq = S.cst[2];
    float inv = rsqrtf(m*m*Av + 2.f*m*Bq + Cq + 1e-5f);
    S.a1[t] = ok ? m*inv : 0.f;
    S.a2[t] = ok ? inv   : 0.f;
    S.a3[t] = ok ? 1.f   : 0.f;
  }
  proj_body(S, t,
            br ? convb_w : conv_w,  br ? convb_b : conv_b,
            br ? xprojb_w : xproj_w, br ? dtb_w : dt_w, br ? dtb_b : dt_b);
  // ---- persist tiles for k_scanC ----
  {
    int dd = t >> 3, tt0 = (t & 7)*4;
    f32x4 sv; sv.x = S.sxt[dd*37+tt0];   sv.y = S.sxt[dd*37+tt0+1];
              sv.z = S.sxt[dd*37+tt0+2]; sv.w = S.sxt[dd*37+tt0+3];
    *(f32x4*)(ws + OFF_SXT + (size_t)bi*2048 + dd*32 + tt0) = sv;
    f32x4 dv; dv.x = S.dtt[t*4];   dv.y = S.dtt[t*4+1];
              dv.z = S.dtt[t*4+2]; dv.w = S.dtt[t*4+3];
    *(f32x4*)(ws + OFF_DTT + (size_t)bi*2048 + t*4) = dv;
    if (t < 128){
      f32x4 bv; bv.x = S.bct[t*4];   bv.y = S.bct[t*4+1];
                bv.z = S.bct[t*4+2]; bv.w = S.bct[t*4+3];
      *(f32x4*)(ws + OFF_BCT + (size_t)bi*512 + t*4) = bv;
    }
    if (t < 32){
      ws[OFF_AN + (size_t)bi*64 + t]      = S.a1[t+3];
      ws[OFF_AN + (size_t)bi*64 + 32 + t] = S.a2[t+3];
    }
  }
  // ---- per-chunk (P,Q) ----
  int d = wv*8 + (lane >> 3), n = lane & 7;
  float P = 1.f, Q = 0.f;
  #pragma unroll 4
  for (int tt = 0; tt < CLN; ++tt){
    float dtv = S.dtt[tt*64 + d];
    float xv  = S.sxt[d*37 + tt];
    float bv  = S.bct[tt*16 + n];
    float da  = fexp2(dtv * A2r);
    Q = fmaf(da, Q, dtv * bv * xv);
    P *= da;
  }
  ws[OFF_P + (size_t)bi*512 + t] = P;
  ws[OFF_Q + (size_t)bi*512 + t] = Q;
}

// ---------------- shared scratch for scanC ----------------
struct CSmem {
  float dtt[2][2048];   // [pass][tt*64+d]
  float sxt[2][2368];   // [pass][d*37+tt] padded
  float bct[2][512];    // [pass][tt*16+k]
  float an[2][64];      // [pass][a1 x32, a2 x32]
  float Wz[2][192];     // z-gate consts per branch
  float gw[64], gb[64], lnbs[64];
  float cst[4];
  float vew[64];
  float ylds[CLN*65];
};

// ---------------- K2: tile-load + prefix + replay + gate + epilogue ----------------
__global__ void __launch_bounds__(512) k_scanC(
    const float* pre_w, const float* pre_b, const float* ln_g, const float* ln_b,
    const float* in_w, const float* in_b_w, const float* A_log, const float* A_b_log,
    const float* Dp, const float* Dp_b,
    const float* norm_w, const float* out_w, const float* post_w, const float* post_b,
    const float* __restrict__ ws, float* __restrict__ out){
  __shared__ __align__(16) CSmem C;
  int bi = blockIdx.x;                 // b*32 + c (output tile)
  int c = bi & 31, b = bi >> 5;
  int t = threadIdx.x;
  int lane = t & 63, wv = t >> 6;
  int d = wv*8 + (lane >> 3), n = lane & 7;
  int ti0 = b*32 + c;
  int ti1 = (b+16)*32 + (31-c);
  // ---- issue all tile loads up front ----
  f32x4 dv0 = *(const f32x4*)(ws + OFF_DTT + (size_t)ti0*2048 + t*4);
  f32x4 dv1 = *(const f32x4*)(ws + OFF_DTT + (size_t)ti1*2048 + t*4);
  f32x4 sv0 = *(const f32x4*)(ws + OFF_SXT + (size_t)ti0*2048 + t*4);
  f32x4 sv1 = *(const f32x4*)(ws + OFF_SXT + (size_t)ti1*2048 + t*4);
  f32x4 bv0, bv1, av0, av1;
  if (t < 128){
    bv0 = *(const f32x4*)(ws + OFF_BCT + (size_t)ti0*512 + t*4);
    bv1 = *(const f32x4*)(ws + OFF_BCT + (size_t)ti1*512 + t*4);
  }
  if (t < 16){
    av0 = *(const f32x4*)(ws + OFF_AN + (size_t)ti0*64 + t*4);
    av1 = *(const f32x4*)(ws + OFF_AN + (size_t)ti1*64 + t*4);
  }
  // ---- consts under the load latency ----
  consts_ln(C.gw, C.gb, C.lnbs, C.cst, t, pre_w, pre_b, ln_g, ln_b);
  __syncthreads();
  if (t < 128){
    int brx = t >> 6, dd = t & 63;
    const float* iw = brx ? in_b_w : in_w;
    float s1 = 0.f, s2 = 0.f, s3 = 0.f;
    #pragma unroll 8
    for (int k = 0; k < 64; ++k){
      float w = iw[(64+dd)*64 + k];
      s1 += w * C.gw[k]; s2 += w * C.gb[k]; s3 += w * C.lnbs[k];
    }
    C.Wz[brx][dd] = s1; C.Wz[brx][64+dd] = s2; C.Wz[brx][128+dd] = s3;
  }
  if (t < 64){
    float s = 0.f;
    #pragma unroll 8
    for (int e = 0; e < 64; ++e) s += post_w[e] * out_w[e*64 + t];
    C.vew[t] = s * norm_w[t];
  }
  float A2r0 = -fexp2(A_log[t]   * LOG2E) * LOG2E;
  float A2r1 = -fexp2(A_b_log[t] * LOG2E) * LOG2E;
  float Dp0 = Dp[d], Dp1 = Dp_b[d];
  float pb = post_b[0];
  // ---- write tiles to LDS ----
  {
    int dd = t >> 3, tt0 = (t & 7)*4;
    *(f32x4*)&C.dtt[0][t*4] = dv0;
    *(f32x4*)&C.dtt[1][t*4] = dv1;
    C.sxt[0][dd*37+tt0+0] = sv0.x; C.sxt[0][dd*37+tt0+1] = sv0.y;
    C.sxt[0][dd*37+tt0+2] = sv0.z; C.sxt[0][dd*37+tt0+3] = sv0.w;
    C.sxt[1][dd*37+tt0+0] = sv1.x; C.sxt[1][dd*37+tt0+1] = sv1.y;
    C.sxt[1][dd*37+tt0+2] = sv1.z; C.sxt[1][dd*37+tt0+3] = sv1.w;
    if (t < 128){
      *(f32x4*)&C.bct[0][t*4] = bv0;
      *(f32x4*)&C.bct[1][t*4] = bv1;
    }
    if (t < 16){
      *(f32x4*)&C.an[0][t*4] = av0;
      *(f32x4*)&C.an[1][t*4] = av1;
    }
  }
  __syncthreads();
  // ---- two passes: prefix + replay + gate ----
  #pragma unroll
  for (int pass = 0; pass < 2; ++pass){
    int bq = pass ? b + 16 : b;
    int ch = pass ? 31 - c : c;
    float h = 0.f;
    {
      const float* Pp = ws + OFF_P + (size_t)bq*NCH*512 + t;
      const float* Qp = ws + OFF_Q + (size_t)bq*NCH*512 + t;
      #pragma unroll
      for (int base = 0; base < 32; base += 8){
        if (base < ch){                      // wave-uniform
          float Pa[8], Qa[8];
          #pragma unroll
          for (int j = 0; j < 8; ++j){
            Pa[j] = Pp[(base+j)*512];
            Qa[j] = Qp[(base+j)*512];
          }
          #pragma unroll
          for (int j = 0; j < 8; ++j)
            h = (base + j < ch) ? fmaf(Pa[j], h, Qa[j]) : h;
        }
      }
    }
    float A2r = pass ? A2r1 : A2r0;
    float Dpd = pass ? Dp1 : Dp0;
    float W1z = C.Wz[pass][d], W2z = C.Wz[pass][64+d], W3z = C.Wz[pass][128+d];
    const float* dtt = C.dtt[pass];
    const float* sxt = C.sxt[pass];
    const float* bct = C.bct[pass];
    const float* an  = C.an[pass];
    #pragma unroll 4
    for (int tt = 0; tt < CLN; ++tt){
      float dtv = dtt[tt*64 + d];
      float xv  = sxt[d*37 + tt];
      float bv  = bct[tt*16 + n];
      float cv  = bct[tt*16 + 8 + n];
      float da  = fexp2(dtv * A2r);
      h = fmaf(da, h, dtv * bv * xv);
      float pv = h * cv;
      pv += __shfl_xor(pv, 1, 64);
      pv += __shfl_xor(pv, 2, 64);
      pv += __shfl_xor(pv, 4, 64);
      if (n == 0){
        float y = pv + Dpd * xv;
        float zv = an[tt]*W1z + an[32+tt]*W2z + W3z;
        float g = fsilu(zv);
        int row = pass ? (31 - tt) : tt;
        if (pass == 0) C.ylds[row*65 + d] = y * g;
        else           C.ylds[row*65 + d] += y * g;
      }
    }
  }
  __syncthreads();
  // ---- epilogue: rmsnorm + collapsed matvec + sigmoid ----
  float ve = C.vew[lane];
  #pragma unroll
  for (int j = 0; j < 4; ++j){
    int row = wv*4 + j;
    float v = C.ylds[row*65 + lane];
    float ss = v*v, dp = v*ve;
    #pragma unroll
    for (int o = 1; o < 64; o <<= 1){
      ss += __shfl_xor(ss, o, 64);
      dp += __shfl_xor(dp, o, 64);
    }
    if (lane == 0){
      float rstd = rsqrtf(ss*(1.f/64.f) + 1e-5f);
      out[b*1024 + c*CLN + row] = fsigmoid(dp*rstd + pb);
    }
  }
}

extern "C" void kernel_launch(void* const* d_in, const int* in_sizes, int n_in,
                              void* d_out, int out_size, void* d_ws, size_t ws_size,
                              hipStream_t stream){
  const float* img1      = (const float*)d_in[0];
  const float* img2      = (const float*)d_in[1];
  const float* pre_w     = (const float*)d_in[2];
  const float* pre_b     = (const float*)d_in[3];
  const float* ln_g      = (const float*)d_in[4];
  const float* ln_b      = (const float*)d_in[5];
  const float* in_w      = (const float*)d_in[6];
  const float* in_b_w    = (const float*)d_in[7];
  const float* conv_w    = (const float*)d_in[8];
  const float* conv_bias = (const float*)d_in[9];
  const float* convb_w   = (const float*)d_in[10];
  const float* convb_bias= (const float*)d_in[11];
  const float* xproj_w   = (const float*)d_in[12];
  const float* xprojb_w  = (const float*)d_in[13];
  const float* dt_w      = (const float*)d_in[14];
  const float* dt_bias   = (const float*)d_in[15];
  const float* dtb_w     = (const float*)d_in[16];
  const float* dtb_bias  = (const float*)d_in[17];
  const float* A_log     = (const float*)d_in[18];
  const float* A_b_log   = (const float*)d_in[19];
  const float* Dp        = (const float*)d_in[20];
  const float* Dp_b      = (const float*)d_in[21];
  const float* norm_w    = (const float*)d_in[22];
  const float* out_w     = (const float*)d_in[23];
  const float* post_w    = (const float*)d_in[24];
  const float* post_b    = (const float*)d_in[25];
  float* ws  = (float*)d_ws;
  float* out = (float*)d_out;

  k_projA<<<1024, 512, 0, stream>>>(img1, img2, pre_w, pre_b, ln_g, ln_b,
                                    in_w, in_b_w, A_log, A_b_log,
                                    conv_w, conv_bias, convb_w, convb_bias,
                                    xproj_w, xprojb_w, dt_w, dt_bias, dtb_w, dtb_bias,
                                    ws);
  k_scanC<<<512, 512, 0, stream>>>(pre_w, pre_b, ln_g, ln_b,
                                   in_w, in_b_w, A_log, A_b_log,
                                   Dp, Dp_b, norm_w, out_w, post_w, post_b,
                                   ws, out);
}

// Round 10
// 74.510 us; speedup vs baseline: 2.7536x; 1.0741x over previous
//
#include <hip/hip_runtime.h>
#include <math.h>

typedef float f32x4 __attribute__((ext_vector_type(4)));

#define NCH 32   // scan chunks
#define CLN 32   // chunk length

// workspace float offsets (~33.8 MB)
#define OFF_P   0          // [1024][512]
#define OFF_Q   524288     // [1024][512]
#define OFF_DTT 1048576    // [1024][2048]  dt tiles [tt][d]
#define OFF_SXT 3145728    // [1024][2048]  silu(conv(x)) tiles [d][tt]
#define OFF_BCT 5242880    // [1024][512]   B/C tiles [tt][k]
#define OFF_AN  5767168    // [1024][64]    normalized pool scalars a1[32],a2[32]
#define OFF_HIN 5832704    // [1024][512]   chunk-prefix h
#define OFF_YF  6356992    // [2*16][1024][64]
#define OFF_WZ  8454144    // [2][192] z-gate consts
#define OFF_VEW 8454528    // [64]
#define OFF_AL2 8454592    // [2][512]

#define LOG2E 1.4426950408889634f
#define LN2   0.6931471805599453f

__device__ __forceinline__ float fexp2(float x){ return __builtin_amdgcn_exp2f(x); }
__device__ __forceinline__ float flog2(float x){ return __builtin_amdgcn_logf(x); }
__device__ __forceinline__ float frcp (float x){ return __builtin_amdgcn_rcpf(x); }
__device__ __forceinline__ float fsigmoid(float x){ return frcp(1.f + fexp2(-x*LOG2E)); }
__device__ __forceinline__ float fsilu(float x){ return x * fsigmoid(x); }
__device__ __forceinline__ float fsoftplus(float x){
  return fmaxf(x, 0.f) + LN2 * flog2(1.f + fexp2(-fabsf(x)*LOG2E));
}

__device__ __forceinline__ float wave_rsum(float v){
  #pragma unroll
  for (int o = 1; o < 64; o <<= 1) v += __shfl_xor(v, o, 64);
  return v;
}
__device__ __forceinline__ float wave_rmax(float v){
  #pragma unroll
  for (int o = 1; o < 64; o <<= 1) v = fmaxf(v, __shfl_xor(v, o, 64));
  return v;
}

// ---------------- shared scratch for projA ----------------
struct Smem {
  float a1[36], a2[36], a3[36];
  float xpt[20*65];     // padded stride 65
  float dtlr[32*4];
  float sxt[64*37];     // [d][ll] stride 37
  float dtt[32*64];     // [ll][d]
  float bct[32*16];     // [ll][k]
  float gw[64], gb[64], lnbs[64];
  float W[384];         // this branch's {W1,W2,W3}x128
  float cst[4];         // Av, Bq, Cq
};

__device__ __forceinline__ void consts_ln(float* gw, float* gb, float* lnbs, float* cst, int t,
    const float* pre_w, const float* pre_b, const float* ln_g, const float* ln_b){
  if (t < 64){
    float w = pre_w[t], b = pre_b[t];
    float mw = wave_rsum(w) * (1.f/64.f);
    float mb = wave_rsum(b) * (1.f/64.f);
    float wc = w - mw, bc = b - mb;
    float Av = wave_rsum(wc*wc) * (1.f/64.f);
    float Bq = wave_rsum(wc*bc) * (1.f/64.f);
    float Cq = wave_rsum(bc*bc) * (1.f/64.f);
    gw[t] = wc * ln_g[t];
    gb[t] = bc * ln_g[t];
    lnbs[t] = ln_b[t];
    if (t == 0){ cst[0] = Av; cst[1] = Bq; cst[2] = Cq; }
  }
}

// conv+silu+xproj+dt for one chunk; assumes S.a1/a2/a3 and S.W ready.
__device__ __forceinline__ void proj_body(
    Smem& S, int t,
    const float* __restrict__ cw, const float* __restrict__ cb,
    const float* __restrict__ xpw, const float* __restrict__ dw,
    const float* __restrict__ dbv){
  for (int i = t; i < 20*64; i += 512){
    int k = i >> 6, d = i & 63;
    S.xpt[k*65 + d] = xpw[i];
  }
  __syncthreads();
  {
    int d = t & 63, lq = t >> 6;
    float cw0=cw[d*4], cw1=cw[d*4+1], cw2=cw[d*4+2], cw3=cw[d*4+3];
    float cbd = cb[d];
    float W1d = S.W[d], W2d = S.W[128+d], W3d = S.W[256+d];
    #pragma unroll
    for (int j = 0; j < 4; ++j){
      int ll = lq*4 + j;
      float A1 = cw0*S.a1[ll] + cw1*S.a1[ll+1] + cw2*S.a1[ll+2] + cw3*S.a1[ll+3];
      float A2 = cw0*S.a2[ll] + cw1*S.a2[ll+1] + cw2*S.a2[ll+2] + cw3*S.a2[ll+3];
      float A3 = cw0*S.a3[ll] + cw1*S.a3[ll+1] + cw2*S.a3[ll+2] + cw3*S.a3[ll+3];
      float xc = W1d*A1 + W2d*A2 + W3d*A3 + cbd;
      S.sxt[d*37 + ll] = fsilu(xc);
    }
  }
  __syncthreads();
  {
    int ll = t >> 4, k = t & 15;
    float acc = 0.f;
    #pragma unroll 8
    for (int d = 0; d < 64; ++d) acc += S.xpt[(4+k)*65 + d] * S.sxt[d*37 + ll];
    S.bct[ll*16 + k] = acc;
  }
  if (t < 128){
    int ll = t >> 2, r = t & 3;
    float acc = 0.f;
    #pragma unroll 8
    for (int d = 0; d < 64; ++d) acc += S.xpt[r*65 + d] * S.sxt[d*37 + ll];
    S.dtlr[ll*4 + r] = acc;
  }
  __syncthreads();
  {
    int d = t & 63, lq = t >> 6;
    float w0=dw[d*4], w1=dw[d*4+1], w2=dw[d*4+2], w3=dw[d*4+3];
    float bd = dbv[d];
    #pragma unroll
    for (int j = 0; j < 4; ++j){
      int ll = lq*4 + j;
      float raw = bd + w0*S.dtlr[ll*4] + w1*S.dtlr[ll*4+1]
                     + w2*S.dtlr[ll*4+2] + w3*S.dtlr[ll*4+3];
      S.dtt[ll*64 + d] = fsoftplus(raw);
    }
  }
  __syncthreads();
}

// ---------------- K1: fused pool + consts + proj + persist tiles + P,Q ----------------
__global__ void __launch_bounds__(512) k_projA(
    const float* __restrict__ img1, const float* __restrict__ img2,
    const float* pre_w, const float* pre_b, const float* ln_g, const float* ln_b,
    const float* in_w, const float* in_b_w, const float* A_log, const float* A_b_log,
    const float* conv_w, const float* conv_b, const float* convb_w, const float* convb_b,
    const float* xproj_w, const float* xprojb_w,
    const float* dt_w, const float* dt_b, const float* dtb_w, const float* dtb_b,
    const float* norm_w, const float* out_w, const float* post_w,
    float* __restrict__ ws){
  __shared__ __align__(16) Smem S;
  int bi = blockIdx.x;                 // bq*32 + c
  int c = bi & 31, bq = bi >> 5, br = bq >> 4, b = bq & 15;
  int t = threadIdx.x;
  int wv = t >> 6, lane = t & 63;
  // ---- pool: each wave loads its rows (35 rows incl 3-row halo) ----
  const float* img = br ? img2 : img1;
  #pragma unroll
  for (int k = 0; k < 5; ++k){
    int i = wv + k*8;
    if (i < 35){
      bool valid = (c > 0) || (i >= 3);
      if (valid){
        int l = br ? (1026 - c*32 - i) : (c*32 - 3 + i);
        const f32x4* rp = (const f32x4*)(img + ((size_t)(b*1024 + l))*1024) + lane;
        f32x4 q0 = __builtin_nontemporal_load(rp +   0);
        f32x4 q1 = __builtin_nontemporal_load(rp +  64);
        f32x4 q2 = __builtin_nontemporal_load(rp + 128);
        f32x4 q3 = __builtin_nontemporal_load(rp + 192);
        float m = fmaxf(fmaxf(fmaxf(q0.x,q0.y), fmaxf(q0.z,q0.w)),
                        fmaxf(fmaxf(q1.x,q1.y), fmaxf(q1.z,q1.w)));
        m = fmaxf(m, fmaxf(fmaxf(fmaxf(q2.x,q2.y), fmaxf(q2.z,q2.w)),
                           fmaxf(fmaxf(q3.x,q3.y), fmaxf(q3.z,q3.w))));
        m = wave_rmax(m);
        if (lane == 0) S.a1[i] = m;
      } else if (lane == 0) S.a1[i] = 0.f;
    }
  }
  // ---- consts (overlap with load drain) ----
  consts_ln(S.gw, S.gb, S.lnbs, S.cst, t, pre_w, pre_b, ln_g, ln_b);
  __syncthreads();
  if (t < 128){
    const float* iw = br ? in_b_w : in_w;
    float s1 = 0.f, s2 = 0.f, s3 = 0.f;
    #pragma unroll 8
    for (int d = 0; d < 64; ++d){
      float w = iw[t*64 + d];
      s1 += w * S.gw[d]; s2 += w * S.gb[d]; s3 += w * S.lnbs[d];
    }
    S.W[      t] = s1;
    S.W[128 + t] = s2;
    S.W[256 + t] = s3;
  }
  float A2r = -fexp2((br ? A_b_log : A_log)[t] * LOG2E) * LOG2E;
  __syncthreads();
  // ---- convert raw max -> a1/a2/a3 ----
  if (t < 36){
    bool ok = (t < 35) && ((c > 0) || (t >= 3));
    float m = ok ? S.a1[t] : 0.f;
    float Av = S.cst[0], Bq = S.cst[1], Cq = S.cst[2];
    float inv = rsqrtf(m*m*Av + 2.f*m*Bq + Cq + 1e-5f);
    S.a1[t] = ok ? m*inv : 0.f;
    S.a2[t] = ok ? inv   : 0.f;
    S.a3[t] = ok ? 1.f   : 0.f;
  }
  proj_body(S, t,
            br ? convb_w : conv_w,  br ? convb_b : conv_b,
            br ? xprojb_w : xproj_w, br ? dtb_w : dt_w, br ? dtb_b : dt_b);
  // ---- persist tiles for projY ----
  {
    int dd = t >> 3, tt0 = (t & 7)*4;
    f32x4 sv; sv.x = S.sxt[dd*37+tt0];   sv.y = S.sxt[dd*37+tt0+1];
              sv.z = S.sxt[dd*37+tt0+2]; sv.w = S.sxt[dd*37+tt0+3];
    *(f32x4*)(ws + OFF_SXT + (size_t)bi*2048 + dd*32 + tt0) = sv;
    f32x4 dv; dv.x = S.dtt[t*4];   dv.y = S.dtt[t*4+1];
              dv.z = S.dtt[t*4+2]; dv.w = S.dtt[t*4+3];
    *(f32x4*)(ws + OFF_DTT + (size_t)bi*2048 + t*4) = dv;
    if (t < 128){
      f32x4 bv; bv.x = S.bct[t*4];   bv.y = S.bct[t*4+1];
                bv.z = S.bct[t*4+2]; bv.w = S.bct[t*4+3];
      *(f32x4*)(ws + OFF_BCT + (size_t)bi*512 + t*4) = bv;
    }
    if (t < 32){
      ws[OFF_AN + (size_t)bi*64 + t]      = S.a1[t+3];
      ws[OFF_AN + (size_t)bi*64 + 32 + t] = S.a2[t+3];
    }
  }
  // ---- blocks 0 / 512 persist per-branch consts for projY/epi ----
  if (bi == 0 || bi == 512){
    ws[OFF_AL2 + br*512 + t] = A2r;
    if (t < 64){
      ws[OFF_WZ + br*192 +       t] = S.W[64 + t];
      ws[OFF_WZ + br*192 +  64 + t] = S.W[128 + 64 + t];
      ws[OFF_WZ + br*192 + 128 + t] = S.W[256 + 64 + t];
    }
    if (bi == 0 && t < 64){
      float s = 0.f;
      #pragma unroll 8
      for (int e = 0; e < 64; ++e) s += post_w[e] * out_w[e*64 + t];
      ws[OFF_VEW + t] = s * norm_w[t];
    }
  }
  // ---- per-chunk (P,Q) ----
  int d = wv*8 + (lane >> 3), n = lane & 7;
  float P = 1.f, Q = 0.f;
  #pragma unroll 4
  for (int tt = 0; tt < CLN; ++tt){
    float dtv = S.dtt[tt*64 + d];
    float xv  = S.sxt[d*37 + tt];
    float bv  = S.bct[tt*16 + n];
    float da  = fexp2(dtv * A2r);
    Q = fmaf(da, Q, dtv * bv * xv);
    P *= da;
  }
  ws[OFF_P + (size_t)bi*512 + t] = P;
  ws[OFF_Q + (size_t)bi*512 + t] = Q;
}

// ---------------- K2: combine chunk summaries once -> HIN ----------------
__global__ void __launch_bounds__(64) k_scanB(float* __restrict__ ws){
  int gid = blockIdx.x*64 + threadIdx.x;   // 0..16383
  int bq = gid >> 9, dn = gid & 511;
  size_t base = (size_t)bq*NCH*512 + dn;
  float P[NCH], Q[NCH];
  #pragma unroll
  for (int c = 0; c < NCH; ++c){
    P[c] = ws[OFF_P + base + (size_t)c*512];
    Q[c] = ws[OFF_Q + base + (size_t)c*512];
  }
  float h = 0.f;
  #pragma unroll
  for (int c = 0; c < NCH; ++c){
    ws[OFF_HIN + base + (size_t)c*512] = h;
    h = fmaf(P[c], h, Q[c]);
  }
}

// ---------------- K3: load tiles + replay + gate -> YF (1 tile per block) ----------------
__global__ void __launch_bounds__(512) k_projY(
    const float* Dp, const float* Dp_b, float* __restrict__ ws){
  __shared__ __align__(16) struct {
    float dtt[2048];
    float sxt[2368];   // d*37+tt padded
    float bct[512];
    float an[64];
    float ylds[CLN*65];
  } C;
  int bi = blockIdx.x;                 // br*512 + b*32 + ch
  int br = bi >> 9, rem = bi & 511, b = rem >> 5, ch = rem & 31;
  int bq = br*16 + b;
  int ti = bq*32 + ch;
  int t = threadIdx.x;
  int lane = t & 63, wv = t >> 6;
  int d = wv*8 + (lane >> 3), n = lane & 7;
  // ---- issue all loads up front ----
  f32x4 dv = *(const f32x4*)(ws + OFF_DTT + (size_t)ti*2048 + t*4);
  f32x4 sv = *(const f32x4*)(ws + OFF_SXT + (size_t)ti*2048 + t*4);
  float h  = ws[OFF_HIN + (size_t)ti*512 + t];
  float A2r = ws[OFF_AL2 + br*512 + t];
  float W1z = ws[OFF_WZ + br*192 +       d];
  float W2z = ws[OFF_WZ + br*192 +  64 + d];
  float W3z = ws[OFF_WZ + br*192 + 128 + d];
  float Dpd = (br ? Dp_b : Dp)[d];
  f32x4 bv4, av4;
  if (t < 128) bv4 = *(const f32x4*)(ws + OFF_BCT + (size_t)ti*512 + t*4);
  if (t < 16)  av4 = *(const f32x4*)(ws + OFF_AN  + (size_t)ti*64  + t*4);
  // ---- stage LDS ----
  {
    *(f32x4*)&C.dtt[t*4] = dv;
    int dd = t >> 3, tt0 = (t & 7)*4;
    C.sxt[dd*37+tt0+0] = sv.x; C.sxt[dd*37+tt0+1] = sv.y;
    C.sxt[dd*37+tt0+2] = sv.z; C.sxt[dd*37+tt0+3] = sv.w;
    if (t < 128) *(f32x4*)&C.bct[t*4] = bv4;
    if (t < 16)  *(f32x4*)&C.an[t*4]  = av4;
  }
  __syncthreads();
  // ---- replay + gate ----
  #pragma unroll 4
  for (int tt = 0; tt < CLN; ++tt){
    float dtv = C.dtt[tt*64 + d];
    float xv  = C.sxt[d*37 + tt];
    float bv  = C.bct[tt*16 + n];
    float cv  = C.bct[tt*16 + 8 + n];
    float da  = fexp2(dtv * A2r);
    h = fmaf(da, h, dtv * bv * xv);
    float pv = h * cv;
    pv += __shfl_xor(pv, 1, 64);
    pv += __shfl_xor(pv, 2, 64);
    pv += __shfl_xor(pv, 4, 64);
    if (n == 0){
      float y = pv + Dpd * xv;
      float zv = C.an[tt]*W1z + C.an[32+tt]*W2z + W3z;
      float g = fsilu(zv);
      int row = br ? (31 - tt) : tt;
      C.ylds[row*65 + d] = y * g;
    }
  }
  __syncthreads();
  // ---- write YF (bwd rows pre-reversed to output index) ----
  {
    float* yf = ws + OFF_YF + (size_t)bq*1024*64;
    int otile = br ? (31 - ch) : ch;
    int row = t >> 4, c4 = (t & 15)*4;
    f32x4 v;
    v.x = C.ylds[row*65+c4];   v.y = C.ylds[row*65+c4+1];
    v.z = C.ylds[row*65+c4+2]; v.w = C.ylds[row*65+c4+3];
    *(f32x4*)(yf + ((size_t)otile*32 + row)*64 + c4) = v;
  }
}

// ---------------- K4: epilogue: rmsnorm + collapsed matvec + sigmoid ----------------
__global__ void __launch_bounds__(256) k_epi(const float* post_b,
                                             const float* __restrict__ ws,
                                             float* __restrict__ out){
  int wv = threadIdx.x >> 6, lane = threadIdx.x & 63;
  int r0 = (blockIdx.x*4 + wv)*4;        // 4 rows per wave
  float ve = ws[OFF_VEW + lane];
  float pb = post_b[0];
  float va[4];
  #pragma unroll
  for (int r = 0; r < 4; ++r){
    size_t row = (size_t)(r0 + r);
    va[r] = ws[OFF_YF + row*64 + lane] +
            ws[OFF_YF + (size_t)16*1024*64 + row*64 + lane];
  }
  #pragma unroll
  for (int r = 0; r < 4; ++r){
    float v = va[r];
    float ss = v*v, dp = v*ve;
    #pragma unroll
    for (int o = 1; o < 64; o <<= 1){
      ss += __shfl_xor(ss, o, 64);
      dp += __shfl_xor(dp, o, 64);
    }
    if (lane == 0){
      float rstd = rsqrtf(ss*(1.f/64.f) + 1e-5f);
      out[r0 + r] = fsigmoid(dp*rstd + pb);
    }
  }
}

extern "C" void kernel_launch(void* const* d_in, const int* in_sizes, int n_in,
                              void* d_out, int out_size, void* d_ws, size_t ws_size,
                              hipStream_t stream){
  const float* img1      = (const float*)d_in[0];
  const float* img2      = (const float*)d_in[1];
  const float* pre_w     = (const float*)d_in[2];
  const float* pre_b     = (const float*)d_in[3];
  const float* ln_g      = (const float*)d_in[4];
  const float* ln_b      = (const float*)d_in[5];
  const float* in_w      = (const float*)d_in[6];
  const float* in_b_w    = (const float*)d_in[7];
  const float* conv_w    = (const float*)d_in[8];
  const float* conv_bias = (const float*)d_in[9];
  const float* convb_w   = (const float*)d_in[10];
  const float* convb_bias= (const float*)d_in[11];
  const float* xproj_w   = (const float*)d_in[12];
  const float* xprojb_w  = (const float*)d_in[13];
  const float* dt_w      = (const float*)d_in[14];
  const float* dt_bias   = (const float*)d_in[15];
  const float* dtb_w     = (const float*)d_in[16];
  const float* dtb_bias  = (const float*)d_in[17];
  const float* A_log     = (const float*)d_in[18];
  const float* A_b_log   = (const float*)d_in[19];
  const float* Dp        = (const float*)d_in[20];
  const float* Dp_b      = (const float*)d_in[21];
  const float* norm_w    = (const float*)d_in[22];
  const float* out_w     = (const float*)d_in[23];
  const float* post_w    = (const float*)d_in[24];
  const float* post_b    = (const float*)d_in[25];
  float* ws  = (float*)d_ws;
  float* out = (float*)d_out;

  k_projA<<<1024, 512, 0, stream>>>(img1, img2, pre_w, pre_b, ln_g, ln_b,
                                    in_w, in_b_w, A_log, A_b_log,
                                    conv_w, conv_bias, convb_w, convb_bias,
                                    xproj_w, xprojb_w, dt_w, dt_bias, dtb_w, dtb_bias,
                                    norm_w, out_w, post_w, ws);
  k_scanB<<<256, 64, 0, stream>>>(ws);
  k_projY<<<1024, 512, 0, stream>>>(Dp, Dp_b, ws);
  k_epi<<<1024, 256, 0, stream>>>(post_b, ws, out);
}

// Round 11
// 74.190 us; speedup vs baseline: 2.7655x; 1.0043x over previous
//
#include <hip/hip_runtime.h>
#include <math.h>

typedef float f32x4 __attribute__((ext_vector_type(4)));

#define NCH 32   // scan chunks
#define CLN 32   // chunk length

// workspace float offsets (~33.8 MB)
#define OFF_P   0          // [1024][512]
#define OFF_Q   524288     // [1024][512]
#define OFF_DTT 1048576    // [1024][2048]  dt tiles [tt][d]
#define OFF_SXT 3145728    // [1024][2048]  silu(conv(x)) tiles [d][tt]
#define OFF_BCT 5242880    // [1024][512]   B/C tiles [tt][k]
#define OFF_AN  5767168    // [1024][64]    normalized pool scalars a1[32],a2[32]
#define OFF_HIN 5832704    // [1024][512]   chunk-prefix h
#define OFF_YF  6356992    // [2*16][1024][64]
#define OFF_WZ  8454144    // [2][192] z-gate consts
#define OFF_VEW 8454528    // [64]
#define OFF_AL2 8454592    // [2][512]

#define LOG2E 1.4426950408889634f
#define LN2   0.6931471805599453f

__device__ __forceinline__ float fexp2(float x){ return __builtin_amdgcn_exp2f(x); }
__device__ __forceinline__ float flog2(float x){ return __builtin_amdgcn_logf(x); }
__device__ __forceinline__ float frcp (float x){ return __builtin_amdgcn_rcpf(x); }
__device__ __forceinline__ float fsigmoid(float x){ return frcp(1.f + fexp2(-x*LOG2E)); }
__device__ __forceinline__ float fsilu(float x){ return x * fsigmoid(x); }
__device__ __forceinline__ float fsoftplus(float x){
  return fmaxf(x, 0.f) + LN2 * flog2(1.f + fexp2(-fabsf(x)*LOG2E));
}

__device__ __forceinline__ float wave_rsum(float v){
  #pragma unroll
  for (int o = 1; o < 64; o <<= 1) v += __shfl_xor(v, o, 64);
  return v;
}
__device__ __forceinline__ float wave_rmax(float v){
  #pragma unroll
  for (int o = 1; o < 64; o <<= 1) v = fmaxf(v, __shfl_xor(v, o, 64));
  return v;
}

// ---------------- shared scratch for projA ----------------
struct Smem {
  float a1[36], a2[36], a3[36];
  float xpt[20*65];     // padded stride 65
  float dtlr[32*4];
  float sxt[64*37];     // [d][ll] stride 37
  float dtt[32*64];     // [ll][d]
  float bct[32*16];     // [ll][k]
  float gw[64], gb[64], lnbs[64];
  float W[384];         // this branch's {W1,W2,W3}x128
  float cst[4];         // Av, Bq, Cq
};

__device__ __forceinline__ void consts_ln(float* gw, float* gb, float* lnbs, float* cst, int t,
    const float* pre_w, const float* pre_b, const float* ln_g, const float* ln_b){
  if (t < 64){
    float w = pre_w[t], b = pre_b[t];
    float mw = wave_rsum(w) * (1.f/64.f);
    float mb = wave_rsum(b) * (1.f/64.f);
    float wc = w - mw, bc = b - mb;
    float Av = wave_rsum(wc*wc) * (1.f/64.f);
    float Bq = wave_rsum(wc*bc) * (1.f/64.f);
    float Cq = wave_rsum(bc*bc) * (1.f/64.f);
    gw[t] = wc * ln_g[t];
    gb[t] = bc * ln_g[t];
    lnbs[t] = ln_b[t];
    if (t == 0){ cst[0] = Av; cst[1] = Bq; cst[2] = Cq; }
  }
}

// conv+silu+xproj+dt for one chunk; assumes S.a1/a2/a3 and S.W ready.
__device__ __forceinline__ void proj_body(
    Smem& S, int t,
    const float* __restrict__ cw, const float* __restrict__ cb,
    const float* __restrict__ xpw, const float* __restrict__ dw,
    const float* __restrict__ dbv){
  for (int i = t; i < 20*64; i += 512){
    int k = i >> 6, d = i & 63;
    S.xpt[k*65 + d] = xpw[i];
  }
  __syncthreads();
  {
    int d = t & 63, lq = t >> 6;
    float cw0=cw[d*4], cw1=cw[d*4+1], cw2=cw[d*4+2], cw3=cw[d*4+3];
    float cbd = cb[d];
    float W1d = S.W[d], W2d = S.W[128+d], W3d = S.W[256+d];
    #pragma unroll
    for (int j = 0; j < 4; ++j){
      int ll = lq*4 + j;
      float A1 = cw0*S.a1[ll] + cw1*S.a1[ll+1] + cw2*S.a1[ll+2] + cw3*S.a1[ll+3];
      float A2 = cw0*S.a2[ll] + cw1*S.a2[ll+1] + cw2*S.a2[ll+2] + cw3*S.a2[ll+3];
      float A3 = cw0*S.a3[ll] + cw1*S.a3[ll+1] + cw2*S.a3[ll+2] + cw3*S.a3[ll+3];
      float xc = W1d*A1 + W2d*A2 + W3d*A3 + cbd;
      S.sxt[d*37 + ll] = fsilu(xc);
    }
  }
  __syncthreads();
  {
    int ll = t >> 4, k = t & 15;
    float acc = 0.f;
    #pragma unroll 8
    for (int d = 0; d < 64; ++d) acc += S.xpt[(4+k)*65 + d] * S.sxt[d*37 + ll];
    S.bct[ll*16 + k] = acc;
  }
  if (t < 128){
    int ll = t >> 2, r = t & 3;
    float acc = 0.f;
    #pragma unroll 8
    for (int d = 0; d < 64; ++d) acc += S.xpt[r*65 + d] * S.sxt[d*37 + ll];
    S.dtlr[ll*4 + r] = acc;
  }
  __syncthreads();
  {
    int d = t & 63, lq = t >> 6;
    float w0=dw[d*4], w1=dw[d*4+1], w2=dw[d*4+2], w3=dw[d*4+3];
    float bd = dbv[d];
    #pragma unroll
    for (int j = 0; j < 4; ++j){
      int ll = lq*4 + j;
      float raw = bd + w0*S.dtlr[ll*4] + w1*S.dtlr[ll*4+1]
                     + w2*S.dtlr[ll*4+2] + w3*S.dtlr[ll*4+3];
      S.dtt[ll*64 + d] = fsoftplus(raw);
    }
  }
  __syncthreads();
}

// ---------------- K1: fused pool + consts + proj + persist tiles + P,Q ----------------
__global__ void __launch_bounds__(512) k_projA(
    const float* __restrict__ img1, const float* __restrict__ img2,
    const float* pre_w, const float* pre_b, const float* ln_g, const float* ln_b,
    const float* in_w, const float* in_b_w, const float* A_log, const float* A_b_log,
    const float* conv_w, const float* conv_b, const float* convb_w, const float* convb_b,
    const float* xproj_w, const float* xprojb_w,
    const float* dt_w, const float* dt_b, const float* dtb_w, const float* dtb_b,
    const float* norm_w, const float* out_w, const float* post_w,
    float* __restrict__ ws){
  __shared__ __align__(16) Smem S;
  int bi = blockIdx.x;                 // bq*32 + c
  int c = bi & 31, bq = bi >> 5, br = bq >> 4, b = bq & 15;
  int t = threadIdx.x;
  int wv = t >> 6, lane = t & 63;
  // ---- pool: each wave loads its rows (35 rows incl 3-row halo) ----
  const float* img = br ? img2 : img1;
  #pragma unroll
  for (int k = 0; k < 5; ++k){
    int i = wv + k*8;
    if (i < 35){
      bool valid = (c > 0) || (i >= 3);
      if (valid){
        int l = br ? (1026 - c*32 - i) : (c*32 - 3 + i);
        const f32x4* rp = (const f32x4*)(img + ((size_t)(b*1024 + l))*1024) + lane;
        f32x4 q0 = __builtin_nontemporal_load(rp +   0);
        f32x4 q1 = __builtin_nontemporal_load(rp +  64);
        f32x4 q2 = __builtin_nontemporal_load(rp + 128);
        f32x4 q3 = __builtin_nontemporal_load(rp + 192);
        float m = fmaxf(fmaxf(fmaxf(q0.x,q0.y), fmaxf(q0.z,q0.w)),
                        fmaxf(fmaxf(q1.x,q1.y), fmaxf(q1.z,q1.w)));
        m = fmaxf(m, fmaxf(fmaxf(fmaxf(q2.x,q2.y), fmaxf(q2.z,q2.w)),
                           fmaxf(fmaxf(q3.x,q3.y), fmaxf(q3.z,q3.w))));
        m = wave_rmax(m);
        if (lane == 0) S.a1[i] = m;
      } else if (lane == 0) S.a1[i] = 0.f;
    }
  }
  // ---- consts (overlap with load drain) ----
  consts_ln(S.gw, S.gb, S.lnbs, S.cst, t, pre_w, pre_b, ln_g, ln_b);
  __syncthreads();
  if (t < 128){
    const float* iw = br ? in_b_w : in_w;
    float s1 = 0.f, s2 = 0.f, s3 = 0.f;
    #pragma unroll 8
    for (int d = 0; d < 64; ++d){
      float w = iw[t*64 + d];
      s1 += w * S.gw[d]; s2 += w * S.gb[d]; s3 += w * S.lnbs[d];
    }
    S.W[      t] = s1;
    S.W[128 + t] = s2;
    S.W[256 + t] = s3;
  }
  float A2r = -fexp2((br ? A_b_log : A_log)[t] * LOG2E) * LOG2E;
  __syncthreads();
  // ---- convert raw max -> a1/a2/a3 ----
  if (t < 36){
    bool ok = (t < 35) && ((c > 0) || (t >= 3));
    float m = ok ? S.a1[t] : 0.f;
    float Av = S.cst[0], Bq = S.cst[1], Cq = S.cst[2];
    float inv = rsqrtf(m*m*Av + 2.f*m*Bq + Cq + 1e-5f);
    S.a1[t] = ok ? m*inv : 0.f;
    S.a2[t] = ok ? inv   : 0.f;
    S.a3[t] = ok ? 1.f   : 0.f;
  }
  proj_body(S, t,
            br ? convb_w : conv_w,  br ? convb_b : conv_b,
            br ? xprojb_w : xproj_w, br ? dtb_w : dt_w, br ? dtb_b : dt_b);
  // ---- persist tiles for projY ----
  {
    int dd = t >> 3, tt0 = (t & 7)*4;
    f32x4 sv; sv.x = S.sxt[dd*37+tt0];   sv.y = S.sxt[dd*37+tt0+1];
              sv.z = S.sxt[dd*37+tt0+2]; sv.w = S.sxt[dd*37+tt0+3];
    *(f32x4*)(ws + OFF_SXT + (size_t)bi*2048 + dd*32 + tt0) = sv;
    f32x4 dv; dv.x = S.dtt[t*4];   dv.y = S.dtt[t*4+1];
              dv.z = S.dtt[t*4+2]; dv.w = S.dtt[t*4+3];
    *(f32x4*)(ws + OFF_DTT + (size_t)bi*2048 + t*4) = dv;
    if (t < 128){
      f32x4 bv; bv.x = S.bct[t*4];   bv.y = S.bct[t*4+1];
                bv.z = S.bct[t*4+2]; bv.w = S.bct[t*4+3];
      *(f32x4*)(ws + OFF_BCT + (size_t)bi*512 + t*4) = bv;
    }
    if (t < 32){
      ws[OFF_AN + (size_t)bi*64 + t]      = S.a1[t+3];
      ws[OFF_AN + (size_t)bi*64 + 32 + t] = S.a2[t+3];
    }
  }
  // ---- blocks 0 / 512 persist per-branch consts for projY/epi ----
  if (bi == 0 || bi == 512){
    ws[OFF_AL2 + br*512 + t] = A2r;
    if (t < 64){
      ws[OFF_WZ + br*192 +       t] = S.W[64 + t];
      ws[OFF_WZ + br*192 +  64 + t] = S.W[128 + 64 + t];
      ws[OFF_WZ + br*192 + 128 + t] = S.W[256 + 64 + t];
    }
    if (bi == 0 && t < 64){
      float s = 0.f;
      #pragma unroll 8
      for (int e = 0; e < 64; ++e) s += post_w[e] * out_w[e*64 + t];
      ws[OFF_VEW + t] = s * norm_w[t];
    }
  }
  // ---- per-chunk (P,Q) ----
  int d = wv*8 + (lane >> 3), n = lane & 7;
  float P = 1.f, Q = 0.f;
  #pragma unroll 4
  for (int tt = 0; tt < CLN; ++tt){
    float dtv = S.dtt[tt*64 + d];
    float xv  = S.sxt[d*37 + tt];
    float bv  = S.bct[tt*16 + n];
    float da  = fexp2(dtv * A2r);
    Q = fmaf(da, Q, dtv * bv * xv);
    P *= da;
  }
  ws[OFF_P + (size_t)bi*512 + t] = P;
  ws[OFF_Q + (size_t)bi*512 + t] = Q;
}

// ---------------- K2: combine chunk summaries once -> HIN ----------------
__global__ void __launch_bounds__(64) k_scanB(float* __restrict__ ws){
  int gid = blockIdx.x*64 + threadIdx.x;   // 0..16383
  int bq = gid >> 9, dn = gid & 511;
  size_t base = (size_t)bq*NCH*512 + dn;
  float P[NCH], Q[NCH];
  #pragma unroll
  for (int c = 0; c < NCH; ++c){
    P[c] = ws[OFF_P + base + (size_t)c*512];
    Q[c] = ws[OFF_Q + base + (size_t)c*512];
  }
  float h = 0.f;
  #pragma unroll
  for (int c = 0; c < NCH; ++c){
    ws[OFF_HIN + base + (size_t)c*512] = h;
    h = fmaf(P[c], h, Q[c]);
  }
}

// ---------------- K3: load tiles + replay + gate -> YF (1 tile per block) ----------------
__global__ void __launch_bounds__(512) k_projY(
    const float* Dp, const float* Dp_b, float* __restrict__ ws){
  __shared__ __align__(16) struct {
    float dtt[2048];
    float sxt[2368];   // d*37+tt padded
    float bct[512];
    float an[64];
    float ylds[CLN*65];
  } C;
  int bi = blockIdx.x;                 // br*512 + b*32 + ch
  int br = bi >> 9, rem = bi & 511, b = rem >> 5, ch = rem & 31;
  int bq = br*16 + b;
  int ti = bq*32 + ch;
  int t = threadIdx.x;
  int lane = t & 63, wv = t >> 6;
  int d = wv*8 + (lane >> 3), n = lane & 7;
  // ---- issue all loads up front ----
  f32x4 dv = *(const f32x4*)(ws + OFF_DTT + (size_t)ti*2048 + t*4);
  f32x4 sv = *(const f32x4*)(ws + OFF_SXT + (size_t)ti*2048 + t*4);
  float h  = ws[OFF_HIN + (size_t)ti*512 + t];
  float A2r = ws[OFF_AL2 + br*512 + t];
  float W1z = ws[OFF_WZ + br*192 +       d];
  float W2z = ws[OFF_WZ + br*192 +  64 + d];
  float W3z = ws[OFF_WZ + br*192 + 128 + d];
  float Dpd = (br ? Dp_b : Dp)[d];
  f32x4 bv4, av4;
  if (t < 128) bv4 = *(const f32x4*)(ws + OFF_BCT + (size_t)ti*512 + t*4);
  if (t < 16)  av4 = *(const f32x4*)(ws + OFF_AN  + (size_t)ti*64  + t*4);
  // ---- stage LDS ----
  {
    *(f32x4*)&C.dtt[t*4] = dv;
    int dd = t >> 3, tt0 = (t & 7)*4;
    C.sxt[dd*37+tt0+0] = sv.x; C.sxt[dd*37+tt0+1] = sv.y;
    C.sxt[dd*37+tt0+2] = sv.z; C.sxt[dd*37+tt0+3] = sv.w;
    if (t < 128) *(f32x4*)&C.bct[t*4] = bv4;
    if (t < 16)  *(f32x4*)&C.an[t*4]  = av4;
  }
  __syncthreads();
  // ---- replay + gate ----
  #pragma unroll 4
  for (int tt = 0; tt < CLN; ++tt){
    float dtv = C.dtt[tt*64 + d];
    float xv  = C.sxt[d*37 + tt];
    float bv  = C.bct[tt*16 + n];
    float cv  = C.bct[tt*16 + 8 + n];
    float da  = fexp2(dtv * A2r);
    h = fmaf(da, h, dtv * bv * xv);
    float pv = h * cv;
    pv += __shfl_xor(pv, 1, 64);
    pv += __shfl_xor(pv, 2, 64);
    pv += __shfl_xor(pv, 4, 64);
    if (n == 0){
      float y = pv + Dpd * xv;
      float zv = C.an[tt]*W1z + C.an[32+tt]*W2z + W3z;
      float g = fsilu(zv);
      int row = br ? (31 - tt) : tt;
      C.ylds[row*65 + d] = y * g;
    }
  }
  __syncthreads();
  // ---- write YF (bwd rows pre-reversed to output index) ----
  {
    float* yf = ws + OFF_YF + (size_t)bq*1024*64;
    int otile = br ? (31 - ch) : ch;
    int row = t >> 4, c4 = (t & 15)*4;
    f32x4 v;
    v.x = C.ylds[row*65+c4];   v.y = C.ylds[row*65+c4+1];
    v.z = C.ylds[row*65+c4+2]; v.w = C.ylds[row*65+c4+3];
    *(f32x4*)(yf + ((size_t)otile*32 + row)*64 + c4) = v;
  }
}

// ---------------- K4: epilogue: rmsnorm + collapsed matvec + sigmoid ----------------
__global__ void __launch_bounds__(256) k_epi(const float* post_b,
                                             const float* __restrict__ ws,
                                             float* __restrict__ out){
  int wv = threadIdx.x >> 6, lane = threadIdx.x & 63;
  int r0 = (blockIdx.x*4 + wv)*4;        // 4 rows per wave
  float ve = ws[OFF_VEW + lane];
  float pb = post_b[0];
  float va[4];
  #pragma unroll
  for (int r = 0; r < 4; ++r){
    size_t row = (size_t)(r0 + r);
    va[r] = ws[OFF_YF + row*64 + lane] +
            ws[OFF_YF + (size_t)16*1024*64 + row*64 + lane];
  }
  #pragma unroll
  for (int r = 0; r < 4; ++r){
    float v = va[r];
    float ss = v*v, dp = v*ve;
    #pragma unroll
    for (int o = 1; o < 64; o <<= 1){
      ss += __shfl_xor(ss, o, 64);
      dp += __shfl_xor(dp, o, 64);
    }
    if (lane == 0){
      float rstd = rsqrtf(ss*(1.f/64.f) + 1e-5f);
      out[r0 + r] = fsigmoid(dp*rstd + pb);
    }
  }
}

extern "C" void kernel_launch(void* const* d_in, const int* in_sizes, int n_in,
                              void* d_out, int out_size, void* d_ws, size_t ws_size,
                              hipStream_t stream){
  const float* img1      = (const float*)d_in[0];
  const float* img2      = (const float*)d_in[1];
  const float* pre_w     = (const float*)d_in[2];
  const float* pre_b     = (const float*)d_in[3];
  const float* ln_g      = (const float*)d_in[4];
  const float* ln_b      = (const float*)d_in[5];
  const float* in_w      = (const float*)d_in[6];
  const float* in_b_w    = (const float*)d_in[7];
  const float* conv_w    = (const float*)d_in[8];
  const float* conv_bias = (const float*)d_in[9];
  const float* convb_w   = (const float*)d_in[10];
  const float* convb_bias= (const float*)d_in[11];
  const float* xproj_w   = (const float*)d_in[12];
  const float* xprojb_w  = (const float*)d_in[13];
  const float* dt_w      = (const float*)d_in[14];
  const float* dt_bias   = (const float*)d_in[15];
  const float* dtb_w     = (const float*)d_in[16];
  const float* dtb_bias  = (const float*)d_in[17];
  const float* A_log     = (const float*)d_in[18];
  const float* A_b_log   = (const float*)d_in[19];
  const float* Dp        = (const float*)d_in[20];
  const float* Dp_b      = (const float*)d_in[21];
  const float* norm_w    = (const float*)d_in[22];
  const float* out_w     = (const float*)d_in[23];
  const float* post_w    = (const float*)d_in[24];
  const float* post_b    = (const float*)d_in[25];
  float* ws  = (float*)d_ws;
  float* out = (float*)d_out;

  k_projA<<<1024, 512, 0, stream>>>(img1, img2, pre_w, pre_b, ln_g, ln_b,
                                    in_w, in_b_w, A_log, A_b_log,
                                    conv_w, conv_bias, convb_w, convb_bias,
                                    xproj_w, xprojb_w, dt_w, dt_bias, dtb_w, dtb_bias,
                                    norm_w, out_w, post_w, ws);
  k_scanB<<<256, 64, 0, stream>>>(ws);
  k_projY<<<1024, 512, 0, stream>>>(Dp, Dp_b, ws);
  k_epi<<<1024, 256, 0, stream>>>(post_b, ws, out);
}

// Round 12
// 73.744 us; speedup vs baseline: 2.7822x; 1.0061x over previous
//
#include <hip/hip_runtime.h>
#include <math.h>

typedef float f32x4 __attribute__((ext_vector_type(4)));

#define NCH 32   // scan chunks
#define CLN 32   // chunk length

// workspace float offsets (~33.8 MB)
#define OFF_P   0          // [1024][512]
#define OFF_Q   524288     // [1024][512]
#define OFF_DTT 1048576    // [1024][2048]  dt tiles [tt][d]
#define OFF_SXT 3145728    // [1024][2048]  silu(conv(x)) tiles [d][tt]
#define OFF_BCT 5242880    // [1024][512]   B/C tiles [tt][k]
#define OFF_AN  5767168    // [1024][64]    normalized pool scalars a1[32],a2[32]
#define OFF_HIN 5832704    // [1024][512]   chunk-prefix h
#define OFF_YF  6356992    // [2*16][1024][64]
#define OFF_WZ  8454144    // [2][192] z-gate consts
#define OFF_VEW 8454528    // [64]
#define OFF_AL2 8454592    // [2][512]

#define LOG2E 1.4426950408889634f
#define LN2   0.6931471805599453f

__device__ __forceinline__ float fexp2(float x){ return __builtin_amdgcn_exp2f(x); }
__device__ __forceinline__ float flog2(float x){ return __builtin_amdgcn_logf(x); }
__device__ __forceinline__ float frcp (float x){ return __builtin_amdgcn_rcpf(x); }
__device__ __forceinline__ float fsigmoid(float x){ return frcp(1.f + fexp2(-x*LOG2E)); }
__device__ __forceinline__ float fsilu(float x){ return x * fsigmoid(x); }
__device__ __forceinline__ float fsoftplus(float x){
  return fmaxf(x, 0.f) + LN2 * flog2(1.f + fexp2(-fabsf(x)*LOG2E));
}

__device__ __forceinline__ float wave_rsum(float v){
  #pragma unroll
  for (int o = 1; o < 64; o <<= 1) v += __shfl_xor(v, o, 64);
  return v;
}
__device__ __forceinline__ float wave_rmax(float v){
  #pragma unroll
  for (int o = 1; o < 64; o <<= 1) v = fmaxf(v, __shfl_xor(v, o, 64));
  return v;
}

// ---------------- shared scratch for projA ----------------
struct Smem {
  float a1[36], a2[36], a3[36];
  float xpt[20*65];     // padded stride 65
  float dtlr[32*4];
  float sxt[64*37];     // [d][ll] stride 37
  float dtt[32*64];     // [ll][d]
  float bct[32*16];     // [ll][k]
  float gw[64], gb[64], lnbs[64];
  float W[384];         // this branch's {W1,W2,W3}x128
  float cst[4];         // Av, Bq, Cq
};

__device__ __forceinline__ void consts_ln(float* gw, float* gb, float* lnbs, float* cst, int t,
    const float* pre_w, const float* pre_b, const float* ln_g, const float* ln_b){
  if (t < 64){
    float w = pre_w[t], b = pre_b[t];
    float mw = wave_rsum(w) * (1.f/64.f);
    float mb = wave_rsum(b) * (1.f/64.f);
    float wc = w - mw, bc = b - mb;
    float Av = wave_rsum(wc*wc) * (1.f/64.f);
    float Bq = wave_rsum(wc*bc) * (1.f/64.f);
    float Cq = wave_rsum(bc*bc) * (1.f/64.f);
    gw[t] = wc * ln_g[t];
    gb[t] = bc * ln_g[t];
    lnbs[t] = ln_b[t];
    if (t == 0){ cst[0] = Av; cst[1] = Bq; cst[2] = Cq; }
  }
}

// conv+silu+xproj+dt for one chunk; assumes S.a1/a2/a3 and S.W ready.
__device__ __forceinline__ void proj_body(
    Smem& S, int t,
    const float* __restrict__ cw, const float* __restrict__ cb,
    const float* __restrict__ xpw, const float* __restrict__ dw,
    const float* __restrict__ dbv){
  for (int i = t; i < 20*64; i += 512){
    int k = i >> 6, d = i & 63;
    S.xpt[k*65 + d] = xpw[i];
  }
  __syncthreads();
  {
    int d = t & 63, lq = t >> 6;
    float cw0=cw[d*4], cw1=cw[d*4+1], cw2=cw[d*4+2], cw3=cw[d*4+3];
    float cbd = cb[d];
    float W1d = S.W[d], W2d = S.W[128+d], W3d = S.W[256+d];
    #pragma unroll
    for (int j = 0; j < 4; ++j){
      int ll = lq*4 + j;
      float A1 = cw0*S.a1[ll] + cw1*S.a1[ll+1] + cw2*S.a1[ll+2] + cw3*S.a1[ll+3];
      float A2 = cw0*S.a2[ll] + cw1*S.a2[ll+1] + cw2*S.a2[ll+2] + cw3*S.a2[ll+3];
      float A3 = cw0*S.a3[ll] + cw1*S.a3[ll+1] + cw2*S.a3[ll+2] + cw3*S.a3[ll+3];
      float xc = W1d*A1 + W2d*A2 + W3d*A3 + cbd;
      S.sxt[d*37 + ll] = fsilu(xc);
    }
  }
  __syncthreads();
  {
    int ll = t >> 4, k = t & 15;
    float acc = 0.f;
    #pragma unroll 8
    for (int d = 0; d < 64; ++d) acc += S.xpt[(4+k)*65 + d] * S.sxt[d*37 + ll];
    S.bct[ll*16 + k] = acc;
  }
  if (t < 128){
    int ll = t >> 2, r = t & 3;
    float acc = 0.f;
    #pragma unroll 8
    for (int d = 0; d < 64; ++d) acc += S.xpt[r*65 + d] * S.sxt[d*37 + ll];
    S.dtlr[ll*4 + r] = acc;
  }
  __syncthreads();
  {
    int d = t & 63, lq = t >> 6;
    float w0=dw[d*4], w1=dw[d*4+1], w2=dw[d*4+2], w3=dw[d*4+3];
    float bd = dbv[d];
    #pragma unroll
    for (int j = 0; j < 4; ++j){
      int ll = lq*4 + j;
      float raw = bd + w0*S.dtlr[ll*4] + w1*S.dtlr[ll*4+1]
                     + w2*S.dtlr[ll*4+2] + w3*S.dtlr[ll*4+3];
      S.dtt[ll*64 + d] = fsoftplus(raw);
    }
  }
  __syncthreads();
}

// ---------------- K1: fused pool + consts + proj + persist tiles + P,Q ----------------
__global__ void __launch_bounds__(512) k_projA(
    const float* __restrict__ img1, const float* __restrict__ img2,
    const float* pre_w, const float* pre_b, const float* ln_g, const float* ln_b,
    const float* in_w, const float* in_b_w, const float* A_log, const float* A_b_log,
    const float* conv_w, const float* conv_b, const float* convb_w, const float* convb_b,
    const float* xproj_w, const float* xprojb_w,
    const float* dt_w, const float* dt_b, const float* dtb_w, const float* dtb_b,
    const float* norm_w, const float* out_w, const float* post_w,
    float* __restrict__ ws){
  __shared__ __align__(16) Smem S;
  int bi = blockIdx.x;                 // bq*32 + c
  int c = bi & 31, bq = bi >> 5, br = bq >> 4, b = bq & 15;
  int t = threadIdx.x;
  int wv = t >> 6, lane = t & 63;
  // ---- pool: each wave loads its rows (35 rows incl 3-row halo) ----
  const float* img = br ? img2 : img1;
  #pragma unroll
  for (int k = 0; k < 5; ++k){
    int i = wv + k*8;
    if (i < 35){
      bool valid = (c > 0) || (i >= 3);
      if (valid){
        int l = br ? (1026 - c*32 - i) : (c*32 - 3 + i);
        const f32x4* rp = (const f32x4*)(img + ((size_t)(b*1024 + l))*1024) + lane;
        f32x4 q0 = __builtin_nontemporal_load(rp +   0);
        f32x4 q1 = __builtin_nontemporal_load(rp +  64);
        f32x4 q2 = __builtin_nontemporal_load(rp + 128);
        f32x4 q3 = __builtin_nontemporal_load(rp + 192);
        float m = fmaxf(fmaxf(fmaxf(q0.x,q0.y), fmaxf(q0.z,q0.w)),
                        fmaxf(fmaxf(q1.x,q1.y), fmaxf(q1.z,q1.w)));
        m = fmaxf(m, fmaxf(fmaxf(fmaxf(q2.x,q2.y), fmaxf(q2.z,q2.w)),
                           fmaxf(fmaxf(q3.x,q3.y), fmaxf(q3.z,q3.w))));
        m = wave_rmax(m);
        if (lane == 0) S.a1[i] = m;
      } else if (lane == 0) S.a1[i] = 0.f;
    }
  }
  // ---- consts (overlap with load drain) ----
  consts_ln(S.gw, S.gb, S.lnbs, S.cst, t, pre_w, pre_b, ln_g, ln_b);
  __syncthreads();
  if (t < 128){
    const float* iw = br ? in_b_w : in_w;
    float s1 = 0.f, s2 = 0.f, s3 = 0.f;
    #pragma unroll 8
    for (int d = 0; d < 64; ++d){
      float w = iw[t*64 + d];
      s1 += w * S.gw[d]; s2 += w * S.gb[d]; s3 += w * S.lnbs[d];
    }
    S.W[      t] = s1;
    S.W[128 + t] = s2;
    S.W[256 + t] = s3;
  }
  float A2r = -fexp2((br ? A_b_log : A_log)[t] * LOG2E) * LOG2E;
  __syncthreads();
  // ---- convert raw max -> a1/a2/a3 ----
  if (t < 36){
    bool ok = (t < 35) && ((c > 0) || (t >= 3));
    float m = ok ? S.a1[t] : 0.f;
    float Av = S.cst[0], Bq = S.cst[1], Cq = S.cst[2];
    float inv = rsqrtf(m*m*Av + 2.f*m*Bq + Cq + 1e-5f);
    S.a1[t] = ok ? m*inv : 0.f;
    S.a2[t] = ok ? inv   : 0.f;
    S.a3[t] = ok ? 1.f   : 0.f;
  }
  proj_body(S, t,
            br ? convb_w : conv_w,  br ? convb_b : conv_b,
            br ? xprojb_w : xproj_w, br ? dtb_w : dt_w, br ? dtb_b : dt_b);
  // ---- persist tiles for projY ----
  {
    int dd = t >> 3, tt0 = (t & 7)*4;
    f32x4 sv; sv.x = S.sxt[dd*37+tt0];   sv.y = S.sxt[dd*37+tt0+1];
              sv.z = S.sxt[dd*37+tt0+2]; sv.w = S.sxt[dd*37+tt0+3];
    *(f32x4*)(ws + OFF_SXT + (size_t)bi*2048 + dd*32 + tt0) = sv;
    f32x4 dv; dv.x = S.dtt[t*4];   dv.y = S.dtt[t*4+1];
              dv.z = S.dtt[t*4+2]; dv.w = S.dtt[t*4+3];
    *(f32x4*)(ws + OFF_DTT + (size_t)bi*2048 + t*4) = dv;
    if (t < 128){
      f32x4 bv; bv.x = S.bct[t*4];   bv.y = S.bct[t*4+1];
                bv.z = S.bct[t*4+2]; bv.w = S.bct[t*4+3];
      *(f32x4*)(ws + OFF_BCT + (size_t)bi*512 + t*4) = bv;
    }
    if (t < 32){
      ws[OFF_AN + (size_t)bi*64 + t]      = S.a1[t+3];
      ws[OFF_AN + (size_t)bi*64 + 32 + t] = S.a2[t+3];
    }
  }
  // ---- blocks 0 / 512 persist per-branch consts for projY/epi ----
  if (bi == 0 || bi == 512){
    ws[OFF_AL2 + br*512 + t] = A2r;
    if (t < 64){
      ws[OFF_WZ + br*192 +       t] = S.W[64 + t];
      ws[OFF_WZ + br*192 +  64 + t] = S.W[128 + 64 + t];
      ws[OFF_WZ + br*192 + 128 + t] = S.W[256 + 64 + t];
    }
    if (bi == 0 && t < 64){
      float s = 0.f;
      #pragma unroll 8
      for (int e = 0; e < 64; ++e) s += post_w[e] * out_w[e*64 + t];
      ws[OFF_VEW + t] = s * norm_w[t];
    }
  }
  // ---- per-chunk (P,Q) ----
  int d = wv*8 + (lane >> 3), n = lane & 7;
  float P = 1.f, Q = 0.f;
  #pragma unroll 4
  for (int tt = 0; tt < CLN; ++tt){
    float dtv = S.dtt[tt*64 + d];
    float xv  = S.sxt[d*37 + tt];
    float bv  = S.bct[tt*16 + n];
    float da  = fexp2(dtv * A2r);
    Q = fmaf(da, Q, dtv * bv * xv);
    P *= da;
  }
  ws[OFF_P + (size_t)bi*512 + t] = P;
  ws[OFF_Q + (size_t)bi*512 + t] = Q;
}

// ---------------- K2: combine chunk summaries once -> HIN ----------------
__global__ void __launch_bounds__(64) k_scanB(float* __restrict__ ws){
  int gid = blockIdx.x*64 + threadIdx.x;   // 0..16383
  int bq = gid >> 9, dn = gid & 511;
  size_t base = (size_t)bq*NCH*512 + dn;
  float P[NCH], Q[NCH];
  #pragma unroll
  for (int c = 0; c < NCH; ++c){
    P[c] = ws[OFF_P + base + (size_t)c*512];
    Q[c] = ws[OFF_Q + base + (size_t)c*512];
  }
  float h = 0.f;
  #pragma unroll
  for (int c = 0; c < NCH; ++c){
    ws[OFF_HIN + base + (size_t)c*512] = h;
    h = fmaf(P[c], h, Q[c]);
  }
}

// ---------------- K3: load tiles + replay + gate -> YF (1 tile per block) ----------------
__global__ void __launch_bounds__(512) k_projY(
    const float* Dp, const float* Dp_b, float* __restrict__ ws){
  __shared__ __align__(16) struct {
    float dtt[2048];
    float sxt[2368];   // d*37+tt padded
    float bct[512];
    float an[64];
    float ylds[CLN*65];
  } C;
  int bi = blockIdx.x;                 // br*512 + b*32 + ch
  int br = bi >> 9, rem = bi & 511, b = rem >> 5, ch = rem & 31;
  int bq = br*16 + b;
  int ti = bq*32 + ch;
  int t = threadIdx.x;
  int lane = t & 63, wv = t >> 6;
  int d = wv*8 + (lane >> 3), n = lane & 7;
  // ---- issue all loads up front ----
  f32x4 dv = *(const f32x4*)(ws + OFF_DTT + (size_t)ti*2048 + t*4);
  f32x4 sv = *(const f32x4*)(ws + OFF_SXT + (size_t)ti*2048 + t*4);
  float h  = ws[OFF_HIN + (size_t)ti*512 + t];
  float A2r = ws[OFF_AL2 + br*512 + t];
  float W1z = ws[OFF_WZ + br*192 +       d];
  float W2z = ws[OFF_WZ + br*192 +  64 + d];
  float W3z = ws[OFF_WZ + br*192 + 128 + d];
  float Dpd = (br ? Dp_b : Dp)[d];
  f32x4 bv4, av4;
  if (t < 128) bv4 = *(const f32x4*)(ws + OFF_BCT + (size_t)ti*512 + t*4);
  if (t < 16)  av4 = *(const f32x4*)(ws + OFF_AN  + (size_t)ti*64  + t*4);
  // ---- stage LDS ----
  {
    *(f32x4*)&C.dtt[t*4] = dv;
    int dd = t >> 3, tt0 = (t & 7)*4;
    C.sxt[dd*37+tt0+0] = sv.x; C.sxt[dd*37+tt0+1] = sv.y;
    C.sxt[dd*37+tt0+2] = sv.z; C.sxt[dd*37+tt0+3] = sv.w;
    if (t < 128) *(f32x4*)&C.bct[t*4] = bv4;
    if (t < 16)  *(f32x4*)&C.an[t*4]  = av4;
  }
  __syncthreads();
  // ---- replay + gate ----
  #pragma unroll 4
  for (int tt = 0; tt < CLN; ++tt){
    float dtv = C.dtt[tt*64 + d];
    float xv  = C.sxt[d*37 + tt];
    float bv  = C.bct[tt*16 + n];
    float cv  = C.bct[tt*16 + 8 + n];
    float da  = fexp2(dtv * A2r);
    h = fmaf(da, h, dtv * bv * xv);
    float pv = h * cv;
    pv += __shfl_xor(pv, 1, 64);
    pv += __shfl_xor(pv, 2, 64);
    pv += __shfl_xor(pv, 4, 64);
    if (n == 0){
      float y = pv + Dpd * xv;
      float zv = C.an[tt]*W1z + C.an[32+tt]*W2z + W3z;
      float g = fsilu(zv);
      int row = br ? (31 - tt) : tt;
      C.ylds[row*65 + d] = y * g;
    }
  }
  __syncthreads();
  // ---- write YF (bwd rows pre-reversed to output index) ----
  {
    float* yf = ws + OFF_YF + (size_t)bq*1024*64;
    int otile = br ? (31 - ch) : ch;
    int row = t >> 4, c4 = (t & 15)*4;
    f32x4 v;
    v.x = C.ylds[row*65+c4];   v.y = C.ylds[row*65+c4+1];
    v.z = C.ylds[row*65+c4+2]; v.w = C.ylds[row*65+c4+3];
    *(f32x4*)(yf + ((size_t)otile*32 + row)*64 + c4) = v;
  }
}

// ---------------- K4: epilogue: rmsnorm + collapsed matvec + sigmoid ----------------
__global__ void __launch_bounds__(256) k_epi(const float* post_b,
                                             const float* __restrict__ ws,
                                             float* __restrict__ out){
  int wv = threadIdx.x >> 6, lane = threadIdx.x & 63;
  int r0 = (blockIdx.x*4 + wv)*4;        // 4 rows per wave
  float ve = ws[OFF_VEW + lane];
  float pb = post_b[0];
  float va[4];
  #pragma unroll
  for (int r = 0; r < 4; ++r){
    size_t row = (size_t)(r0 + r);
    va[r] = ws[OFF_YF + row*64 + lane] +
            ws[OFF_YF + (size_t)16*1024*64 + row*64 + lane];
  }
  #pragma unroll
  for (int r = 0; r < 4; ++r){
    float v = va[r];
    float ss = v*v, dp = v*ve;
    #pragma unroll
    for (int o = 1; o < 64; o <<= 1){
      ss += __shfl_xor(ss, o, 64);
      dp += __shfl_xor(dp, o, 64);
    }
    if (lane == 0){
      float rstd = rsqrtf(ss*(1.f/64.f) + 1e-5f);
      out[r0 + r] = fsigmoid(dp*rstd + pb);
    }
  }
}

extern "C" void kernel_launch(void* const* d_in, const int* in_sizes, int n_in,
                              void* d_out, int out_size, void* d_ws, size_t ws_size,
                              hipStream_t stream){
  const float* img1      = (const float*)d_in[0];
  const float* img2      = (const float*)d_in[1];
  const float* pre_w     = (const float*)d_in[2];
  const float* pre_b     = (const float*)d_in[3];
  const float* ln_g      = (const float*)d_in[4];
  const float* ln_b      = (const float*)d_in[5];
  const float* in_w      = (const float*)d_in[6];
  const float* in_b_w    = (const float*)d_in[7];
  const float* conv_w    = (const float*)d_in[8];
  const float* conv_bias = (const float*)d_in[9];
  const float* convb_w   = (const float*)d_in[10];
  const float* convb_bias= (const float*)d_in[11];
  const float* xproj_w   = (const float*)d_in[12];
  const float* xprojb_w  = (const float*)d_in[13];
  const float* dt_w      = (const float*)d_in[14];
  const float* dt_bias   = (const float*)d_in[15];
  const float* dtb_w     = (const float*)d_in[16];
  const float* dtb_bias  = (const float*)d_in[17];
  const float* A_log     = (const float*)d_in[18];
  const float* A_b_log   = (const float*)d_in[19];
  const float* Dp        = (const float*)d_in[20];
  const float* Dp_b      = (const float*)d_in[21];
  const float* norm_w    = (const float*)d_in[22];
  const float* out_w     = (const float*)d_in[23];
  const float* post_w    = (const float*)d_in[24];
  const float* post_b    = (const float*)d_in[25];
  float* ws  = (float*)d_ws;
  float* out = (float*)d_out;

  k_projA<<<1024, 512, 0, stream>>>(img1, img2, pre_w, pre_b, ln_g, ln_b,
                                    in_w, in_b_w, A_log, A_b_log,
                                    conv_w, conv_bias, convb_w, convb_bias,
                                    xproj_w, xprojb_w, dt_w, dt_bias, dtb_w, dtb_bias,
                                    norm_w, out_w, post_w, ws);
  k_scanB<<<256, 64, 0, stream>>>(ws);
  k_projY<<<1024, 512, 0, stream>>>(Dp, Dp_b, ws);
  k_epi<<<1024, 256, 0, stream>>>(post_b, ws, out);
}

// Round 13
// 71.291 us; speedup vs baseline: 2.8779x; 1.0344x over previous
//
#include <hip/hip_runtime.h>
#include <math.h>

typedef float f32x4 __attribute__((ext_vector_type(4)));

#define NCH 32   // scan chunks
#define CLN 32   // chunk length

// workspace float offsets
#define OFF_P   0          // [1024][512]
#define OFF_Q   524288     // [1024][512]
#define OFF_DTT 1048576    // [1024][2048]  dt tiles [tt][d]
#define OFF_SXT 3145728    // [1024][2048]  silu(conv(x)) tiles [d][tt]
#define OFF_BCT 5242880    // [1024][512]   B/C tiles [tt][k]
#define OFF_AN  5767168    // [1024][64]    normalized pool scalars a1[32],a2[32]
#define OFF_HIN 5832704    // [1024][512]   chunk-prefix h
#define OFF_WZ  6356992    // [2][192] z-gate consts
#define OFF_VEW 6357376    // [64]
#define OFF_AL2 6357440    // [2][512]

#define LOG2E 1.4426950408889634f
#define LN2   0.6931471805599453f

__device__ __forceinline__ float fexp2(float x){ return __builtin_amdgcn_exp2f(x); }
__device__ __forceinline__ float flog2(float x){ return __builtin_amdgcn_logf(x); }
__device__ __forceinline__ float frcp (float x){ return __builtin_amdgcn_rcpf(x); }
__device__ __forceinline__ float fsigmoid(float x){ return frcp(1.f + fexp2(-x*LOG2E)); }
__device__ __forceinline__ float fsilu(float x){ return x * fsigmoid(x); }
__device__ __forceinline__ float fsoftplus(float x){
  return fmaxf(x, 0.f) + LN2 * flog2(1.f + fexp2(-fabsf(x)*LOG2E));
}

__device__ __forceinline__ float wave_rsum(float v){
  #pragma unroll
  for (int o = 1; o < 64; o <<= 1) v += __shfl_xor(v, o, 64);
  return v;
}
__device__ __forceinline__ float wave_rmax(float v){
  #pragma unroll
  for (int o = 1; o < 64; o <<= 1) v = fmaxf(v, __shfl_xor(v, o, 64));
  return v;
}

// ---------------- shared scratch for projA ----------------
struct Smem {
  float a1[36], a2[36], a3[36];
  float xpt[20*65];     // padded stride 65
  float dtlr[32*4];
  float sxt[64*37];     // [d][ll] stride 37
  float dtt[32*64];     // [ll][d]
  float bct[32*16];     // [ll][k]
  float gw[64], gb[64], lnbs[64];
  float W[384];         // this branch's {W1,W2,W3}x128
  float cst[4];         // Av, Bq, Cq
};

__device__ __forceinline__ void consts_ln(float* gw, float* gb, float* lnbs, float* cst, int t,
    const float* pre_w, const float* pre_b, const float* ln_g, const float* ln_b){
  if (t < 64){
    float w = pre_w[t], b = pre_b[t];
    float mw = wave_rsum(w) * (1.f/64.f);
    float mb = wave_rsum(b) * (1.f/64.f);
    float wc = w - mw, bc = b - mb;
    float Av = wave_rsum(wc*wc) * (1.f/64.f);
    float Bq = wave_rsum(wc*bc) * (1.f/64.f);
    float Cq = wave_rsum(bc*bc) * (1.f/64.f);
    gw[t] = wc * ln_g[t];
    gb[t] = bc * ln_g[t];
    lnbs[t] = ln_b[t];
    if (t == 0){ cst[0] = Av; cst[1] = Bq; cst[2] = Cq; }
  }
}

// conv+silu+xproj+dt for one chunk; assumes S.a1/a2/a3 and S.W ready.
__device__ __forceinline__ void proj_body(
    Smem& S, int t,
    const float* __restrict__ cw, const float* __restrict__ cb,
    const float* __restrict__ xpw, const float* __restrict__ dw,
    const float* __restrict__ dbv){
  for (int i = t; i < 20*64; i += 512){
    int k = i >> 6, d = i & 63;
    S.xpt[k*65 + d] = xpw[i];
  }
  __syncthreads();
  {
    int d = t & 63, lq = t >> 6;
    float cw0=cw[d*4], cw1=cw[d*4+1], cw2=cw[d*4+2], cw3=cw[d*4+3];
    float cbd = cb[d];
    float W1d = S.W[d], W2d = S.W[128+d], W3d = S.W[256+d];
    #pragma unroll
    for (int j = 0; j < 4; ++j){
      int ll = lq*4 + j;
      float A1 = cw0*S.a1[ll] + cw1*S.a1[ll+1] + cw2*S.a1[ll+2] + cw3*S.a1[ll+3];
      float A2 = cw0*S.a2[ll] + cw1*S.a2[ll+1] + cw2*S.a2[ll+2] + cw3*S.a2[ll+3];
      float A3 = cw0*S.a3[ll] + cw1*S.a3[ll+1] + cw2*S.a3[ll+2] + cw3*S.a3[ll+3];
      float xc = W1d*A1 + W2d*A2 + W3d*A3 + cbd;
      S.sxt[d*37 + ll] = fsilu(xc);
    }
  }
  __syncthreads();
  {
    int ll = t >> 4, k = t & 15;
    float acc = 0.f;
    #pragma unroll 8
    for (int d = 0; d < 64; ++d) acc += S.xpt[(4+k)*65 + d] * S.sxt[d*37 + ll];
    S.bct[ll*16 + k] = acc;
  }
  if (t < 128){
    int ll = t >> 2, r = t & 3;
    float acc = 0.f;
    #pragma unroll 8
    for (int d = 0; d < 64; ++d) acc += S.xpt[r*65 + d] * S.sxt[d*37 + ll];
    S.dtlr[ll*4 + r] = acc;
  }
  __syncthreads();
  {
    int d = t & 63, lq = t >> 6;
    float w0=dw[d*4], w1=dw[d*4+1], w2=dw[d*4+2], w3=dw[d*4+3];
    float bd = dbv[d];
    #pragma unroll
    for (int j = 0; j < 4; ++j){
      int ll = lq*4 + j;
      float raw = bd + w0*S.dtlr[ll*4] + w1*S.dtlr[ll*4+1]
                     + w2*S.dtlr[ll*4+2] + w3*S.dtlr[ll*4+3];
      S.dtt[ll*64 + d] = fsoftplus(raw);
    }
  }
  __syncthreads();
}

// ---------------- K1: fused pool + consts + proj + persist tiles + P,Q ----------------
__global__ void __launch_bounds__(512) k_projA(
    const float* __restrict__ img1, const float* __restrict__ img2,
    const float* pre_w, const float* pre_b, const float* ln_g, const float* ln_b,
    const float* in_w, const float* in_b_w, const float* A_log, const float* A_b_log,
    const float* conv_w, const float* conv_b, const float* convb_w, const float* convb_b,
    const float* xproj_w, const float* xprojb_w,
    const float* dt_w, const float* dt_b, const float* dtb_w, const float* dtb_b,
    const float* norm_w, const float* out_w, const float* post_w,
    float* __restrict__ ws){
  __shared__ __align__(16) Smem S;
  int bi = blockIdx.x;                 // bq*32 + c
  int c = bi & 31, bq = bi >> 5, br = bq >> 4, b = bq & 15;
  int t = threadIdx.x;
  int wv = t >> 6, lane = t & 63;
  // ---- pool: each wave loads its rows (35 rows incl 3-row halo) ----
  const float* img = br ? img2 : img1;
  #pragma unroll
  for (int k = 0; k < 5; ++k){
    int i = wv + k*8;
    if (i < 35){
      bool valid = (c > 0) || (i >= 3);
      if (valid){
        int l = br ? (1026 - c*32 - i) : (c*32 - 3 + i);
        const f32x4* rp = (const f32x4*)(img + ((size_t)(b*1024 + l))*1024) + lane;
        f32x4 q0 = __builtin_nontemporal_load(rp +   0);
        f32x4 q1 = __builtin_nontemporal_load(rp +  64);
        f32x4 q2 = __builtin_nontemporal_load(rp + 128);
        f32x4 q3 = __builtin_nontemporal_load(rp + 192);
        float m = fmaxf(fmaxf(fmaxf(q0.x,q0.y), fmaxf(q0.z,q0.w)),
                        fmaxf(fmaxf(q1.x,q1.y), fmaxf(q1.z,q1.w)));
        m = fmaxf(m, fmaxf(fmaxf(fmaxf(q2.x,q2.y), fmaxf(q2.z,q2.w)),
                           fmaxf(fmaxf(q3.x,q3.y), fmaxf(q3.z,q3.w))));
        m = wave_rmax(m);
        if (lane == 0) S.a1[i] = m;
      } else if (lane == 0) S.a1[i] = 0.f;
    }
  }
  // ---- consts (overlap with load drain) ----
  consts_ln(S.gw, S.gb, S.lnbs, S.cst, t, pre_w, pre_b, ln_g, ln_b);
  __syncthreads();
  if (t < 128){
    const float* iw = br ? in_b_w : in_w;
    float s1 = 0.f, s2 = 0.f, s3 = 0.f;
    #pragma unroll 8
    for (int d = 0; d < 64; ++d){
      float w = iw[t*64 + d];
      s1 += w * S.gw[d]; s2 += w * S.gb[d]; s3 += w * S.lnbs[d];
    }
    S.W[      t] = s1;
    S.W[128 + t] = s2;
    S.W[256 + t] = s3;
  }
  float A2r = -fexp2((br ? A_b_log : A_log)[t] * LOG2E) * LOG2E;
  __syncthreads();
  // ---- convert raw max -> a1/a2/a3 ----
  if (t < 36){
    bool ok = (t < 35) && ((c > 0) || (t >= 3));
    float m = ok ? S.a1[t] : 0.f;
    float Av = S.cst[0], Bq = S.cst[1], Cq = S.cst[2];
    float inv = rsqrtf(m*m*Av + 2.f*m*Bq + Cq + 1e-5f);
    S.a1[t] = ok ? m*inv : 0.f;
    S.a2[t] = ok ? inv   : 0.f;
    S.a3[t] = ok ? 1.f   : 0.f;
  }
  proj_body(S, t,
            br ? convb_w : conv_w,  br ? convb_b : conv_b,
            br ? xprojb_w : xproj_w, br ? dtb_w : dt_w, br ? dtb_b : dt_b);
  // ---- persist tiles for scanY ----
  {
    int dd = t >> 3, tt0 = (t & 7)*4;
    f32x4 sv; sv.x = S.sxt[dd*37+tt0];   sv.y = S.sxt[dd*37+tt0+1];
              sv.z = S.sxt[dd*37+tt0+2]; sv.w = S.sxt[dd*37+tt0+3];
    *(f32x4*)(ws + OFF_SXT + (size_t)bi*2048 + dd*32 + tt0) = sv;
    f32x4 dv; dv.x = S.dtt[t*4];   dv.y = S.dtt[t*4+1];
              dv.z = S.dtt[t*4+2]; dv.w = S.dtt[t*4+3];
    *(f32x4*)(ws + OFF_DTT + (size_t)bi*2048 + t*4) = dv;
    if (t < 128){
      f32x4 bv; bv.x = S.bct[t*4];   bv.y = S.bct[t*4+1];
                bv.z = S.bct[t*4+2]; bv.w = S.bct[t*4+3];
      *(f32x4*)(ws + OFF_BCT + (size_t)bi*512 + t*4) = bv;
    }
    if (t < 32){
      ws[OFF_AN + (size_t)bi*64 + t]      = S.a1[t+3];
      ws[OFF_AN + (size_t)bi*64 + 32 + t] = S.a2[t+3];
    }
  }
  // ---- blocks 0 / 512 persist per-branch consts for scanY ----
  if (bi == 0 || bi == 512){
    ws[OFF_AL2 + br*512 + t] = A2r;
    if (t < 64){
      ws[OFF_WZ + br*192 +       t] = S.W[64 + t];
      ws[OFF_WZ + br*192 +  64 + t] = S.W[128 + 64 + t];
      ws[OFF_WZ + br*192 + 128 + t] = S.W[256 + 64 + t];
    }
    if (bi == 0 && t < 64){
      float s = 0.f;
      #pragma unroll 8
      for (int e = 0; e < 64; ++e) s += post_w[e] * out_w[e*64 + t];
      ws[OFF_VEW + t] = s * norm_w[t];
    }
  }
  // ---- per-chunk (P,Q) ----
  int d = wv*8 + (lane >> 3), n = lane & 7;
  float P = 1.f, Q = 0.f;
  #pragma unroll 4
  for (int tt = 0; tt < CLN; ++tt){
    float dtv = S.dtt[tt*64 + d];
    float xv  = S.sxt[d*37 + tt];
    float bv  = S.bct[tt*16 + n];
    float da  = fexp2(dtv * A2r);
    Q = fmaf(da, Q, dtv * bv * xv);
    P *= da;
  }
  ws[OFF_P + (size_t)bi*512 + t] = P;
  ws[OFF_Q + (size_t)bi*512 + t] = Q;
}

// ---------------- K2: combine chunk summaries once -> HIN ----------------
__global__ void __launch_bounds__(64) k_scanB(float* __restrict__ ws){
  int gid = blockIdx.x*64 + threadIdx.x;   // 0..16383
  int bq = gid >> 9, dn = gid & 511;
  size_t base = (size_t)bq*NCH*512 + dn;
  float P[NCH], Q[NCH];
  #pragma unroll
  for (int c = 0; c < NCH; ++c){
    P[c] = ws[OFF_P + base + (size_t)c*512];
    Q[c] = ws[OFF_Q + base + (size_t)c*512];
  }
  float h = 0.f;
  #pragma unroll
  for (int c = 0; c < NCH; ++c){
    ws[OFF_HIN + base + (size_t)c*512] = h;
    h = fmaf(P[c], h, Q[c]);
  }
}

// ---------------- K3: fwd+bwd replay + gate + rmsnorm epilogue, no YF ----------------
__global__ void __launch_bounds__(512) k_scanY(
    const float* Dp, const float* Dp_b, const float* post_b,
    const float* __restrict__ ws, float* __restrict__ out){
  __shared__ __align__(16) struct {
    float dtt[2][2048];   // [pass][tt*64+d]
    float sxt[2][2368];   // [pass][d*37+tt] padded
    float bct[2][512];    // [pass][tt*16+k]
    float an[2][64];
    float ylds[CLN*65];
  } C;
  int bi = blockIdx.x;                 // b*32 + oc (output tile)
  int oc = bi & 31, b = bi >> 5;
  int t = threadIdx.x;
  int lane = t & 63, wv = t >> 6;
  int d = wv*8 + (lane >> 3), n = lane & 7;
  int ti0 = b*32 + oc;                 // fwd tile
  int ti1 = (b+16)*32 + (31 - oc);     // matching bwd tile
  // ---- issue all loads up front ----
  f32x4 dv0 = *(const f32x4*)(ws + OFF_DTT + (size_t)ti0*2048 + t*4);
  f32x4 dv1 = *(const f32x4*)(ws + OFF_DTT + (size_t)ti1*2048 + t*4);
  f32x4 sv0 = *(const f32x4*)(ws + OFF_SXT + (size_t)ti0*2048 + t*4);
  f32x4 sv1 = *(const f32x4*)(ws + OFF_SXT + (size_t)ti1*2048 + t*4);
  float h0  = ws[OFF_HIN + (size_t)ti0*512 + t];
  float h1  = ws[OFF_HIN + (size_t)ti1*512 + t];
  float A2r0 = ws[OFF_AL2 +       t];
  float A2r1 = ws[OFF_AL2 + 512 + t];
  float W1z0 = ws[OFF_WZ +       d], W2z0 = ws[OFF_WZ +  64 + d], W3z0 = ws[OFF_WZ + 128 + d];
  float W1z1 = ws[OFF_WZ + 192 + d], W2z1 = ws[OFF_WZ + 256 + d], W3z1 = ws[OFF_WZ + 320 + d];
  float Dp0 = Dp[d], Dp1 = Dp_b[d];
  float ve = ws[OFF_VEW + lane];
  float pb = post_b[0];
  f32x4 bv0, bv1, av0, av1;
  if (t < 128){
    bv0 = *(const f32x4*)(ws + OFF_BCT + (size_t)ti0*512 + t*4);
    bv1 = *(const f32x4*)(ws + OFF_BCT + (size_t)ti1*512 + t*4);
  }
  if (t < 16){
    av0 = *(const f32x4*)(ws + OFF_AN + (size_t)ti0*64 + t*4);
    av1 = *(const f32x4*)(ws + OFF_AN + (size_t)ti1*64 + t*4);
  }
  // ---- stage LDS ----
  {
    *(f32x4*)&C.dtt[0][t*4] = dv0;
    *(f32x4*)&C.dtt[1][t*4] = dv1;
    int dd = t >> 3, tt0 = (t & 7)*4;
    C.sxt[0][dd*37+tt0+0] = sv0.x; C.sxt[0][dd*37+tt0+1] = sv0.y;
    C.sxt[0][dd*37+tt0+2] = sv0.z; C.sxt[0][dd*37+tt0+3] = sv0.w;
    C.sxt[1][dd*37+tt0+0] = sv1.x; C.sxt[1][dd*37+tt0+1] = sv1.y;
    C.sxt[1][dd*37+tt0+2] = sv1.z; C.sxt[1][dd*37+tt0+3] = sv1.w;
    if (t < 128){
      *(f32x4*)&C.bct[0][t*4] = bv0;
      *(f32x4*)&C.bct[1][t*4] = bv1;
    }
    if (t < 16){
      *(f32x4*)&C.an[0][t*4] = av0;
      *(f32x4*)&C.an[1][t*4] = av1;
    }
  }
  __syncthreads();
  // ---- pass 0 (fwd): ylds[tt] = y*g ; pass 1 (bwd): ylds[31-tt] += y*g ----
  // (thread (d,n=0) owns column d in both passes -> no inter-pass sync needed)
  #pragma unroll
  for (int pass = 0; pass < 2; ++pass){
    float h   = pass ? h1 : h0;
    float A2r = pass ? A2r1 : A2r0;
    float Dpd = pass ? Dp1 : Dp0;
    float W1z = pass ? W1z1 : W1z0;
    float W2z = pass ? W2z1 : W2z0;
    float W3z = pass ? W3z1 : W3z0;
    const float* dtt = C.dtt[pass];
    const float* sxt = C.sxt[pass];
    const float* bct = C.bct[pass];
    const float* an  = C.an[pass];
    #pragma unroll 4
    for (int tt = 0; tt < CLN; ++tt){
      float dtv = dtt[tt*64 + d];
      float xv  = sxt[d*37 + tt];
      float bv  = bct[tt*16 + n];
      float cv  = bct[tt*16 + 8 + n];
      float da  = fexp2(dtv * A2r);
      h = fmaf(da, h, dtv * bv * xv);
      float pv = h * cv;
      pv += __shfl_xor(pv, 1, 64);
      pv += __shfl_xor(pv, 2, 64);
      pv += __shfl_xor(pv, 4, 64);
      if (n == 0){
        float y = pv + Dpd * xv;
        float zv = an[tt]*W1z + an[32+tt]*W2z + W3z;
        float g = fsilu(zv);
        int row = pass ? (31 - tt) : tt;
        if (pass == 0) C.ylds[row*65 + d] = y * g;
        else           C.ylds[row*65 + d] += y * g;
      }
    }
  }
  __syncthreads();
  // ---- epilogue: rmsnorm + collapsed matvec + sigmoid; 8 waves x 4 rows ----
  #pragma unroll
  for (int j = 0; j < 4; ++j){
    int row = wv*4 + j;
    float v = C.ylds[row*65 + lane];
    float ss = v*v, dp = v*ve;
    #pragma unroll
    for (int o = 1; o < 64; o <<= 1){
      ss += __shfl_xor(ss, o, 64);
      dp += __shfl_xor(dp, o, 64);
    }
    if (lane == 0){
      float rstd = rsqrtf(ss*(1.f/64.f) + 1e-5f);
      out[b*1024 + oc*32 + row] = fsigmoid(dp*rstd + pb);
    }
  }
}

extern "C" void kernel_launch(void* const* d_in, const int* in_sizes, int n_in,
                              void* d_out, int out_size, void* d_ws, size_t ws_size,
                              hipStream_t stream){
  const float* img1      = (const float*)d_in[0];
  const float* img2      = (const float*)d_in[1];
  const float* pre_w     = (const float*)d_in[2];
  const float* pre_b     = (const float*)d_in[3];
  const float* ln_g      = (const float*)d_in[4];
  const float* ln_b      = (const float*)d_in[5];
  const float* in_w      = (const float*)d_in[6];
  const float* in_b_w    = (const float*)d_in[7];
  const float* conv_w    = (const float*)d_in[8];
  const float* conv_bias = (const float*)d_in[9];
  const float* convb_w   = (const float*)d_in[10];
  const float* convb_bias= (const float*)d_in[11];
  const float* xproj_w   = (const float*)d_in[12];
  const float* xprojb_w  = (const float*)d_in[13];
  const float* dt_w      = (const float*)d_in[14];
  const float* dt_bias   = (const float*)d_in[15];
  const float* dtb_w     = (const float*)d_in[16];
  const float* dtb_bias  = (const float*)d_in[17];
  const float* A_log     = (const float*)d_in[18];
  const float* A_b_log   = (const float*)d_in[19];
  const float* Dp        = (const float*)d_in[20];
  const float* Dp_b      = (const float*)d_in[21];
  const float* norm_w    = (const float*)d_in[22];
  const float* out_w     = (const float*)d_in[23];
  const float* post_w    = (const float*)d_in[24];
  const float* post_b    = (const float*)d_in[25];
  float* ws  = (float*)d_ws;
  float* out = (float*)d_out;

  k_projA<<<1024, 512, 0, stream>>>(img1, img2, pre_w, pre_b, ln_g, ln_b,
                                    in_w, in_b_w, A_log, A_b_log,
                                    conv_w, conv_bias, convb_w, convb_bias,
                                    xproj_w, xprojb_w, dt_w, dt_bias, dtb_w, dtb_bias,
                                    norm_w, out_w, post_w, ws);
  k_scanB<<<256, 64, 0, stream>>>(ws);
  k_scanY<<<512, 512, 0, stream>>>(Dp, Dp_b, post_b, ws, out);
}